// Round 4
// baseline (2179.302 us; speedup 1.0000x reference)
//
#include <hip/hip_runtime.h>
#include <hip/hip_bf16.h>

typedef __hip_bfloat16 bf16;
__device__ __forceinline__ float b2f(bf16 v){ return __bfloat162float(v); }

#define N_NODES 16384
#define N_EDGES 65536
#define NB 256
#define LSEQ 1000
#define BN_EPS 1e-5f
#define W1O 985
#define W2O 970
#define W3O 955

// ---- dtype flag: 1 if float inputs are f32, 0 if bf16 ----
__device__ int g_isf32;

// Load float-input element i from p under flag f (element index, not bytes).
__device__ __forceinline__ float LD(const void* p, int i, int f){
    return f ? ((const float*)p)[i] : b2f(((const bf16*)p)[i]);
}

__global__ void k_dtype(const void* x){
    if (threadIdx.x != 0 || blockIdx.x != 0) return;
    const unsigned short* u = (const unsigned short*)x;
    int insane = 0;
    for (int i = 0; i < 512; i++){
        unsigned short h = u[i];
        int ex = (h >> 7) & 0xFF;          // bf16 exponent field
        if (!(h == 0 || (ex >= 96 && ex <= 142))) insane++;
    }
    g_isf32 = (insane > 50) ? 1 : 0;
}

// ---- all intermediates in device globals ----
__device__ float g_hA[N_NODES*32];
__device__ float g_agg[N_NODES*32];
__device__ float g_pooled[NB*32];
__device__ float g_xd[NB*128];
__device__ float g_P[16*26*32];
__device__ float g_wsum[32*128];
__device__ float g_xdb[NB*32];
__device__ float g_xcm[NB*32];
__device__ float g_xcf[NB*128];
__device__ float g_z1[NB*1024];
__device__ float g_z2[NB*256];
__device__ float g_c1o[NB*W1O*32];   // 32.3 MB
__device__ float g_c2o[NB*W2O*32];   // 31.8 MB

__global__ void k_zero_agg(){ g_agg[blockIdx.x*256 + threadIdx.x] = 0.f; }      // grid 2048
__global__ void k_zero_misc(){                                                   // grid 32
    int i = blockIdx.x*256 + threadIdx.x;
    g_pooled[i] = 0.f;
    g_xcm[i] = 0.f;
}

// ---------------- GIN branch ----------------
// Layer-1 trick: (x+agg)@W1 = x@W1 + segment_sum((x@W1)[src]) since W1 is linear.

__global__ __launch_bounds__(256) void k_proj78(const void* x, const void* W1)
{
    const int F = g_isf32;
    __shared__ float sW1[78*32];
    __shared__ float sx[8][78];
    int tid = threadIdx.x;
    for (int i = tid; i < 78*32; i += 256) sW1[i] = LD(W1, i, F);
    int nodeBase = blockIdx.x * 8;
    for (int i = tid; i < 8*78; i += 256){
        int ln = i / 78, f = i - ln*78;
        sx[ln][f] = LD(x, (nodeBase + ln)*78 + f, F);
    }
    __syncthreads();
    int ln = tid >> 5, j = tid & 31;
    float a = 0.f;
    #pragma unroll 6
    for (int i = 0; i < 78; i++) a += sx[ln][i] * sW1[i*32 + j];
    g_hA[(nodeBase + ln)*32 + j] = a;
}

__global__ void k_scatter32(const int* __restrict__ ei){
    int idx = blockIdx.x*256 + threadIdx.x;      // grid covers N_EDGES*32 exactly
    int e = idx >> 5, f = idx & 31;
    atomicAdd(&g_agg[ei[N_EDGES + e]*32 + f], g_hA[ei[e]*32 + f]);
}

__global__ __launch_bounds__(256) void k_gin1b(
    const void* b1, const void* W2, const void* b2,
    const void* bng, const void* bnb, const void* bnm, const void* bnv)
{
    const int F = g_isf32;
    __shared__ float sW2[32*32];
    __shared__ float sb1[32], sb2[32], sA[32], sB[32];
    __shared__ float st[8][32];
    int tid = threadIdx.x;
    for (int i = tid; i < 1024; i += 256) sW2[i] = LD(W2, i, F);
    if (tid < 32){
        sb1[tid] = LD(b1, tid, F); sb2[tid] = LD(b2, tid, F);
        float inv = LD(bng, tid, F) * rsqrtf(LD(bnv, tid, F) + BN_EPS);
        sA[tid] = inv;
        sB[tid] = LD(bnb, tid, F) - LD(bnm, tid, F) * inv;
    }
    __syncthreads();
    int ln = tid >> 5, j = tid & 31;
    int n = blockIdx.x*8 + ln;
    st[ln][j] = fmaxf(g_hA[n*32 + j] + g_agg[n*32 + j] + sb1[j], 0.f);
    __syncthreads();
    float t2 = sb2[j];
    #pragma unroll
    for (int i = 0; i < 32; i++) t2 += st[ln][i] * sW2[i*32 + j];
    t2 = fmaxf(t2, 0.f);             // relu BEFORE bn (reference order)
    g_hA[n*32 + j] = t2 * sA[j] + sB[j];
}

__global__ __launch_bounds__(256) void k_gin32L(
    const void* W1, const void* b1, const void* W2, const void* b2,
    const void* bng, const void* bnb, const void* bnm, const void* bnv, int l)
{
    const int F = g_isf32;
    const int oW = l*1024, ob = l*32, obn = (l+1)*32;
    __shared__ float sW1[32*32], sW2[32*32];
    __shared__ float sb1[32], sb2[32], sA[32], sB[32];
    __shared__ float sh[8][32], st[8][32];
    int tid = threadIdx.x;
    for (int i = tid; i < 1024; i += 256){ sW1[i] = LD(W1, oW + i, F); sW2[i] = LD(W2, oW + i, F); }
    if (tid < 32){
        sb1[tid] = LD(b1, ob + tid, F); sb2[tid] = LD(b2, ob + tid, F);
        float inv = LD(bng, obn + tid, F) * rsqrtf(LD(bnv, obn + tid, F) + BN_EPS);
        sA[tid] = inv;
        sB[tid] = LD(bnb, obn + tid, F) - LD(bnm, obn + tid, F) * inv;
    }
    int ln = tid >> 5, j = tid & 31;
    int n = blockIdx.x*8 + ln;
    sh[ln][j] = g_hA[n*32 + j] + g_agg[n*32 + j];
    __syncthreads();
    float t1 = sb1[j];
    #pragma unroll
    for (int i = 0; i < 32; i++) t1 += sh[ln][i] * sW1[i*32 + j];
    st[ln][j] = fmaxf(t1, 0.f);
    __syncthreads();
    float t2 = sb2[j];
    #pragma unroll
    for (int i = 0; i < 32; i++) t2 += st[ln][i] * sW2[i*32 + j];
    t2 = fmaxf(t2, 0.f);
    g_hA[n*32 + j] = t2 * sA[j] + sB[j];
}

__global__ void k_pool(const int* __restrict__ batch){
    int idx = blockIdx.x*256 + threadIdx.x;      // exactly 16384*32 threads
    int n = idx >> 5;
    atomicAdd(&g_pooled[batch[n]*32 + (idx & 31)], g_hA[idx]);
}

__global__ void k_xd(const void* W, const void* bias){
    const int F = g_isf32;
    __shared__ float sp[32];
    int b = blockIdx.x, j = threadIdx.x;         // block 128
    if (j < 32) sp[j] = g_pooled[b*32 + j];
    __syncthreads();
    float a = LD(bias, j, F);
    #pragma unroll
    for (int i = 0; i < 32; i++) a += sp[i] * LD(W, i*128 + j, F);
    g_xd[b*128 + j] = fmaxf(a, 0.f);
}

// ---------------- conv1 via 26-row embedding table ----------------

__global__ void k_P(const void* embed, const void* c1W){
    const int F = g_isf32;
    int idx = blockIdx.x*256 + threadIdx.x;
    if (idx >= 16*26*32) return;
    int o = idx & 31;
    int t = (idx >> 5) % 26;
    int k = idx / (32*26);
    float a = 0.f;
    for (int c = 0; c < 128; c++)
        a += LD(embed, t*128 + c, F) * LD(c1W, o*4096 + c*16 + k, F);
    g_P[(k*26 + t)*32 + o] = a;
}

__global__ void k_wsum(const void* c1W){
    const int F = g_isf32;
    int idx = blockIdx.x*256 + threadIdx.x;      // 4096 threads
    int o = idx >> 7, c = idx & 127;
    float a = 0.f;
    #pragma unroll
    for (int k = 0; k < 16; k++) a += LD(c1W, o*4096 + (128 + c)*16 + k, F);
    g_wsum[o*128 + c] = a;
}

__global__ void k_xdbias(const void* c1b){
    const int F = g_isf32;
    int idx = blockIdx.x*256 + threadIdx.x;      // 8192 threads
    int b = idx >> 5, o = idx & 31;
    float a = LD(c1b, o, F);
    for (int c = 0; c < 128; c++) a += g_xd[b*128 + c] * g_wsum[o*128 + c];
    g_xdb[idx] = a;
}

__global__ __launch_bounds__(256) void k_conv1L(
    const int* __restrict__ target,
    const void* g, const void* be, const void* m, const void* v, int obn)
{
    const int F = g_isf32;
    __shared__ float sP[16*26*32];
    __shared__ int   stg[LSEQ];
    __shared__ float sxb[32], sA[32], sB[32];
    int b = blockIdx.x, tid = threadIdx.x;
    for (int i = tid; i < 16*26*32; i += 256) sP[i] = g_P[i];
    for (int i = tid; i < LSEQ; i += 256) stg[i] = target[b*LSEQ + i];
    if (tid < 32){
        sxb[tid] = g_xdb[b*32 + tid];
        float inv = LD(g, obn + tid, F) * rsqrtf(LD(v, obn + tid, F) + BN_EPS);
        sA[tid] = inv;
        sB[tid] = LD(be, obn + tid, F) - LD(m, obn + tid, F) * inv;
    }
    __syncthreads();
    int o = tid & 31, wsub = tid >> 5;
    for (int w = wsub; w < W1O; w += 8){
        float a = sxb[o];
        #pragma unroll
        for (int k = 0; k < 16; k++)
            a += sP[(k*26 + stg[w + k])*32 + o];
        a = fmaxf(a * sA[o] + sB[o], 0.f);
        g_c1o[(b*W1O + w)*32 + o] = a;
    }
}

// ---------------- conv2/conv3 (32ch -> 32ch, k=16), VALU f32 ----------------
// sel 0: g_c1o -> g_c2o (store). sel 1: g_c2o -> atomicMax g_xcm (post-relu >=0).

__global__ __launch_bounds__(256) void k_convXL(
    int sel, int Win, int Wout, int tiles,
    const void* Wt, const void* bias,
    const void* g, const void* be, const void* m, const void* v, int obn)
{
    const int F = g_isf32;
    const float* in = (sel == 0) ? g_c1o : g_c2o;
    __shared__ float sW[8][32][32];      // half of the k-taps at a time: 32 KB
    __shared__ float sIn[32][80];        // transposed input tile (64 outputs + 15 halo)
    __shared__ float sA[32], sB[32];
    int tid = threadIdx.x;
    unsigned bid = blockIdx.x;
    int b = bid / (unsigned)tiles;
    int tile = bid - b*tiles;
    int w0 = tile * 64;

    for (int i = tid; i < 80*32; i += 256){
        int c = i & 31, wlr = i >> 5;
        int wg = w0 + wlr;
        sIn[c][wlr] = (wg < Win) ? in[(b*Win + wg)*32 + c] : 0.f;
    }
    if (tid < 32){
        float inv = LD(g, obn + tid, F) * rsqrtf(LD(v, obn + tid, F) + BN_EPS);
        sA[tid] = inv;
        sB[tid] = LD(be, obn + tid, F) + (LD(bias, tid, F) - LD(m, obn + tid, F)) * inv;
    }

    int wl = tid & 63;
    int og = tid >> 6;                   // 4 groups of 8 output channels
    int w = w0 + wl;
    float acc[8];
    #pragma unroll
    for (int j = 0; j < 8; j++) acc[j] = 0.f;

    for (int kh = 0; kh < 2; kh++){
        __syncthreads();                 // protects sIn staging (kh=0) and sW reuse (kh=1)
        for (int i = tid; i < 8*32*32; i += 256){
            int o = i & 31, c = (i >> 5) & 31, k8 = i >> 10;
            sW[k8][c][o] = LD(Wt, o*512 + c*16 + (kh*8 + k8), F);
        }
        __syncthreads();
        if (w < Wout){
            #pragma unroll
            for (int k8 = 0; k8 < 8; k8++)
                #pragma unroll
                for (int c = 0; c < 32; c++){
                    float a = sIn[c][wl + kh*8 + k8];
                    #pragma unroll
                    for (int j = 0; j < 8; j++)
                        acc[j] += a * sW[k8][c][og*8 + j];
                }
        }
    }
    if (w < Wout){
        #pragma unroll
        for (int j = 0; j < 8; j++){
            int o = og*8 + j;
            float y = fmaxf(acc[j] * sA[o] + sB[o], 0.f);
            if (sel == 0) g_c2o[(b*Wout + w)*32 + o] = y;
            else atomicMax((int*)&g_xcm[b*32 + o], __float_as_int(y));
        }
    }
}

// ---------------- FC tail ----------------

__global__ void k_xcf(const void* W, const void* bias,
                      const void* g, const void* be, const void* m, const void* v){
    const int F = g_isf32;
    __shared__ float sp[32];
    int b = blockIdx.x, j = threadIdx.x;         // block 128
    if (j < 32) sp[j] = g_xcm[b*32 + j];
    __syncthreads();
    float a = LD(bias, j, F);
    #pragma unroll
    for (int i = 0; i < 32; i++) a += sp[i] * LD(W, i*128 + j, F);
    float inv = LD(g, j, F) * rsqrtf(LD(v, j, F) + BN_EPS);
    a = (a - LD(m, j, F)) * inv + LD(be, j, F);
    g_xcf[b*128 + j] = fmaxf(a, 0.f);
}

__global__ __launch_bounds__(256) void k_fc1(const void* W, const void* bias){
    const int F = g_isf32;
    __shared__ float sz[256];
    int b = blockIdx.x >> 2;
    int j = ((blockIdx.x & 3) << 8) + threadIdx.x;
    int t = threadIdx.x;
    sz[t] = (t < 128) ? g_xd[b*128 + t] : g_xcf[b*128 + (t - 128)];
    __syncthreads();
    float a = LD(bias, j, F);
    for (int i = 0; i < 256; i++) a += sz[i] * LD(W, i*1024 + j, F);
    g_z1[b*1024 + j] = fmaxf(a, 0.f);
}

__global__ __launch_bounds__(256) void k_fc2(const void* W, const void* bias){
    const int F = g_isf32;
    __shared__ float sz[1024];
    int b = blockIdx.x, t = threadIdx.x;
    for (int i = t; i < 1024; i += 256) sz[i] = g_z1[b*1024 + i];
    __syncthreads();
    float a = LD(bias, t, F);
    for (int i = 0; i < 1024; i++) a += sz[i] * LD(W, i*256 + t, F);
    g_z2[b*256 + t] = fmaxf(a, 0.f);
}

__global__ void k_out(const void* W, const void* bias, void* out){
    const int F = g_isf32;
    __shared__ float red[256];
    int b = blockIdx.x, t = threadIdx.x;
    red[t] = g_z2[b*256 + t] * LD(W, t, F);
    __syncthreads();
    for (int s = 128; s > 0; s >>= 1){
        if (t < s) red[t] += red[t + s];
        __syncthreads();
    }
    if (t == 0){
        float r = red[0] + LD(bias, 0, F);
        if (F) ((float*)out)[b] = r;
        else   ((bf16*)out)[b] = __float2bfloat16(r);
    }
}

// ---------------- launch ----------------

extern "C" void kernel_launch(void* const* d_in, const int* in_sizes, int n_in,
                              void* d_out, int out_size, void* d_ws, size_t ws_size,
                              hipStream_t stream)
{
    (void)in_sizes; (void)n_in; (void)out_size; (void)d_ws; (void)ws_size;
    const void* x      = d_in[0];
    const int*  ei     = (const int*)d_in[1];
    const int*  batch  = (const int*)d_in[2];
    const int*  target = (const int*)d_in[3];
    const void* g1W1 = d_in[4];  const void* g1b1 = d_in[5];
    const void* g1W2 = d_in[6];  const void* g1b2 = d_in[7];
    const void* gW1  = d_in[8];  const void* gb1  = d_in[9];
    const void* gW2  = d_in[10]; const void* gb2  = d_in[11];
    const void* bng  = d_in[12]; const void* bnb  = d_in[13];
    const void* bnm  = d_in[14]; const void* bnv  = d_in[15];
    const void* fcxdW = d_in[16]; const void* fcxdb = d_in[17];
    const void* embed = d_in[18];
    const void* c1W = d_in[19]; const void* c1b = d_in[20];
    const void* c2W = d_in[21]; const void* c2b = d_in[22];
    const void* c3W = d_in[23]; const void* c3b = d_in[24];
    const void* cbng = d_in[25]; const void* cbnb = d_in[26];
    const void* cbnm = d_in[27]; const void* cbnv = d_in[28];
    const void* fcxcW = d_in[29]; const void* fcxcb = d_in[30];
    const void* bnfcg = d_in[31]; const void* bnfcb = d_in[32];
    const void* bnfcm = d_in[33]; const void* bnfcv = d_in[34];
    const void* fc1W = d_in[35]; const void* fc1b = d_in[36];
    const void* fc2W = d_in[37]; const void* fc2b = d_in[38];
    const void* outW = d_in[39]; const void* outb = d_in[40];

    // ---- dtype detector first (writes g_isf32; stream-ordered) ----
    k_dtype<<<1, 64, 0, stream>>>(x);

    // ---- GIN layer 1 (projected scatter) ----
    k_proj78<<<N_NODES/8, 256, 0, stream>>>(x, g1W1);
    k_zero_agg<<<N_NODES*32/256, 256, 0, stream>>>();
    k_zero_misc<<<NB*32/256, 256, 0, stream>>>();
    k_scatter32<<<(N_EDGES*32)/256, 256, 0, stream>>>(ei);
    k_gin1b<<<N_NODES/8, 256, 0, stream>>>(g1b1, g1W2, g1b2, bng, bnb, bnm, bnv);
    // ---- GIN layers 2..5 (stacked params; element offsets applied in-kernel) ----
    for (int l = 0; l < 4; l++){
        k_zero_agg<<<N_NODES*32/256, 256, 0, stream>>>();
        k_scatter32<<<(N_EDGES*32)/256, 256, 0, stream>>>(ei);
        k_gin32L<<<N_NODES/8, 256, 0, stream>>>(gW1, gb1, gW2, gb2,
                                                bng, bnb, bnm, bnv, l);
    }
    // ---- pool + xd ----
    k_pool<<<(N_NODES*32)/256, 256, 0, stream>>>(batch);
    k_xd<<<NB, 128, 0, stream>>>(fcxdW, fcxdb);
    // ---- conv1 prep (embedding-table trick) ----
    k_P<<<(16*26*32 + 255)/256, 256, 0, stream>>>(embed, c1W);
    k_wsum<<<16, 256, 0, stream>>>(c1W);
    k_xdbias<<<32, 256, 0, stream>>>(c1b);
    // ---- conv chain ----
    k_conv1L<<<NB, 256, 0, stream>>>(target, cbng, cbnb, cbnm, cbnv, 0);
    k_convXL<<<NB*16, 256, 0, stream>>>(0, W1O, W2O, 16, c2W, c2b,
                                        cbng, cbnb, cbnm, cbnv, 32);
    k_convXL<<<NB*15, 256, 0, stream>>>(1, W2O, W3O, 15, c3W, c3b,
                                        cbng, cbnb, cbnm, cbnv, 64);
    // ---- FC tail ----
    k_xcf<<<NB, 128, 0, stream>>>(fcxcW, fcxcb, bnfcg, bnfcb, bnfcm, bnfcv);
    k_fc1<<<NB*4, 256, 0, stream>>>(fc1W, fc1b);
    k_fc2<<<NB, 256, 0, stream>>>(fc2W, fc2b);
    k_out<<<NB, 256, 0, stream>>>(outW, outb, d_out);
}

// Round 5
// 1135.627 us; speedup vs baseline: 1.9190x; 1.9190x over previous
//
#include <hip/hip_runtime.h>
#include <hip/hip_bf16.h>

typedef __hip_bfloat16 bf16;
__device__ __forceinline__ float b2f(bf16 v){ return __bfloat162float(v); }

#define N_NODES 16384
#define N_EDGES 65536
#define NB 256
#define LSEQ 1000
#define BN_EPS 1e-5f
#define W1O 985
#define W2O 970
#define W3O 955
#define C1S 988          // g_c1o row stride (floats), layout [b][32 ch][C1S]
#define C2S 976          // g_c2o row stride (floats), layout [b][32 ch][C2S]

// ---- dtype flag: 1 if float inputs are f32, 0 if bf16 (measured: f32 on this harness) ----
__device__ int g_isf32;

__device__ __forceinline__ float LD(const void* p, int i, int f){
    return f ? ((const float*)p)[i] : b2f(((const bf16*)p)[i]);
}

__global__ void k_dtype(const void* x){
    if (threadIdx.x != 0 || blockIdx.x != 0) return;
    const unsigned short* u = (const unsigned short*)x;
    int insane = 0;
    for (int i = 0; i < 512; i++){
        unsigned short h = u[i];
        int ex = (h >> 7) & 0xFF;
        if (!(h == 0 || (ex >= 96 && ex <= 142))) insane++;
    }
    g_isf32 = (insane > 50) ? 1 : 0;
}

// ---- intermediates in device globals ----
__device__ float g_hA[N_NODES*32];
__device__ float g_agg[N_NODES*32];
__device__ float g_pooled[NB*32];
__device__ float g_xd[NB*128];
__device__ float g_P[16*26*32];
__device__ float g_wsum[32*128];
__device__ float g_xdb[NB*32];
__device__ float g_xcm[NB*32];
__device__ float g_xcf[NB*128];
__device__ float g_z1[NB*1024];
__device__ float g_z2[NB*256];
__device__ float g_c1o[NB*32*C1S];   // 32.4 MB, [b][o][w]
__device__ float g_c2o[NB*32*C2S];   // 32.0 MB, [b][o][w]

__global__ void k_zero_agg(){ g_agg[blockIdx.x*256 + threadIdx.x] = 0.f; }
__global__ void k_zero_misc(){
    int i = blockIdx.x*256 + threadIdx.x;
    g_pooled[i] = 0.f;
    g_xcm[i] = 0.f;
}

// ---------------- GIN branch ----------------

__global__ __launch_bounds__(256) void k_proj78(const void* x, const void* W1)
{
    const int F = g_isf32;
    __shared__ float sW1[78*32];
    __shared__ float sx[8][78];
    int tid = threadIdx.x;
    for (int i = tid; i < 78*32; i += 256) sW1[i] = LD(W1, i, F);
    int nodeBase = blockIdx.x * 8;
    for (int i = tid; i < 8*78; i += 256){
        int ln = i / 78, f = i - ln*78;
        sx[ln][f] = LD(x, (nodeBase + ln)*78 + f, F);
    }
    __syncthreads();
    int ln = tid >> 5, j = tid & 31;
    float a = 0.f;
    #pragma unroll 6
    for (int i = 0; i < 78; i++) a += sx[ln][i] * sW1[i*32 + j];
    g_hA[(nodeBase + ln)*32 + j] = a;
}

__global__ void k_scatter32(const int* __restrict__ ei){
    int idx = blockIdx.x*256 + threadIdx.x;
    int e = idx >> 5, f = idx & 31;
    atomicAdd(&g_agg[ei[N_EDGES + e]*32 + f], g_hA[ei[e]*32 + f]);
}

__global__ __launch_bounds__(256) void k_gin1b(
    const void* b1, const void* W2, const void* b2,
    const void* bng, const void* bnb, const void* bnm, const void* bnv)
{
    const int F = g_isf32;
    __shared__ float sW2[32*32];
    __shared__ float sb1[32], sb2[32], sA[32], sB[32];
    __shared__ float st[8][32];
    int tid = threadIdx.x;
    for (int i = tid; i < 1024; i += 256) sW2[i] = LD(W2, i, F);
    if (tid < 32){
        sb1[tid] = LD(b1, tid, F); sb2[tid] = LD(b2, tid, F);
        float inv = LD(bng, tid, F) * rsqrtf(LD(bnv, tid, F) + BN_EPS);
        sA[tid] = inv;
        sB[tid] = LD(bnb, tid, F) - LD(bnm, tid, F) * inv;
    }
    __syncthreads();
    int ln = tid >> 5, j = tid & 31;
    int n = blockIdx.x*8 + ln;
    st[ln][j] = fmaxf(g_hA[n*32 + j] + g_agg[n*32 + j] + sb1[j], 0.f);
    __syncthreads();
    float t2 = sb2[j];
    #pragma unroll
    for (int i = 0; i < 32; i++) t2 += st[ln][i] * sW2[i*32 + j];
    t2 = fmaxf(t2, 0.f);
    g_hA[n*32 + j] = t2 * sA[j] + sB[j];
}

__global__ __launch_bounds__(256) void k_gin32L(
    const void* W1, const void* b1, const void* W2, const void* b2,
    const void* bng, const void* bnb, const void* bnm, const void* bnv, int l)
{
    const int F = g_isf32;
    const int oW = l*1024, ob = l*32, obn = (l+1)*32;
    __shared__ float sW1[32*32], sW2[32*32];
    __shared__ float sb1[32], sb2[32], sA[32], sB[32];
    __shared__ float sh[8][32], st[8][32];
    int tid = threadIdx.x;
    for (int i = tid; i < 1024; i += 256){ sW1[i] = LD(W1, oW + i, F); sW2[i] = LD(W2, oW + i, F); }
    if (tid < 32){
        sb1[tid] = LD(b1, ob + tid, F); sb2[tid] = LD(b2, ob + tid, F);
        float inv = LD(bng, obn + tid, F) * rsqrtf(LD(bnv, obn + tid, F) + BN_EPS);
        sA[tid] = inv;
        sB[tid] = LD(bnb, obn + tid, F) - LD(bnm, obn + tid, F) * inv;
    }
    int ln = tid >> 5, j = tid & 31;
    int n = blockIdx.x*8 + ln;
    sh[ln][j] = g_hA[n*32 + j] + g_agg[n*32 + j];
    __syncthreads();
    float t1 = sb1[j];
    #pragma unroll
    for (int i = 0; i < 32; i++) t1 += sh[ln][i] * sW1[i*32 + j];
    st[ln][j] = fmaxf(t1, 0.f);
    __syncthreads();
    float t2 = sb2[j];
    #pragma unroll
    for (int i = 0; i < 32; i++) t2 += st[ln][i] * sW2[i*32 + j];
    t2 = fmaxf(t2, 0.f);
    g_hA[n*32 + j] = t2 * sA[j] + sB[j];
}

__global__ void k_pool(const int* __restrict__ batch){
    int idx = blockIdx.x*256 + threadIdx.x;
    int n = idx >> 5;
    atomicAdd(&g_pooled[batch[n]*32 + (idx & 31)], g_hA[idx]);
}

__global__ void k_xd(const void* W, const void* bias){
    const int F = g_isf32;
    __shared__ float sp[32];
    int b = blockIdx.x, j = threadIdx.x;
    if (j < 32) sp[j] = g_pooled[b*32 + j];
    __syncthreads();
    float a = LD(bias, j, F);
    #pragma unroll
    for (int i = 0; i < 32; i++) a += sp[i] * LD(W, i*128 + j, F);
    g_xd[b*128 + j] = fmaxf(a, 0.f);
}

// ---------------- conv1 via 26-row embedding table ----------------

__global__ void k_P(const void* embed, const void* c1W){
    const int F = g_isf32;
    int idx = blockIdx.x*256 + threadIdx.x;
    if (idx >= 16*26*32) return;
    int o = idx & 31;
    int t = (idx >> 5) % 26;
    int k = idx / (32*26);
    float a = 0.f;
    for (int c = 0; c < 128; c++)
        a += LD(embed, t*128 + c, F) * LD(c1W, o*4096 + c*16 + k, F);
    g_P[(k*26 + t)*32 + o] = a;
}

__global__ void k_wsum(const void* c1W){
    const int F = g_isf32;
    int idx = blockIdx.x*256 + threadIdx.x;
    int o = idx >> 7, c = idx & 127;
    float a = 0.f;
    #pragma unroll
    for (int k = 0; k < 16; k++) a += LD(c1W, o*4096 + (128 + c)*16 + k, F);
    g_wsum[o*128 + c] = a;
}

__global__ void k_xdbias(const void* c1b){
    const int F = g_isf32;
    int idx = blockIdx.x*256 + threadIdx.x;
    int b = idx >> 5, o = idx & 31;
    float a = LD(c1b, o, F);
    for (int c = 0; c < 128; c++) a += g_xd[b*128 + c] * g_wsum[o*128 + c];
    g_xdb[idx] = a;
}

// writes [b][o][w] layout (stride C1S) for coalesced conv2 staging
__global__ __launch_bounds__(256) void k_conv1L(
    const int* __restrict__ target,
    const void* g, const void* be, const void* m, const void* v, int obn)
{
    const int F = g_isf32;
    __shared__ float sP[16*26*32];
    __shared__ int   stg[LSEQ];
    __shared__ float sxb[32], sA[32], sB[32];
    int b = blockIdx.x, tid = threadIdx.x;
    for (int i = tid; i < 16*26*32; i += 256) sP[i] = g_P[i];
    for (int i = tid; i < LSEQ; i += 256) stg[i] = target[b*LSEQ + i];
    if (tid < 32){
        sxb[tid] = g_xdb[b*32 + tid];
        float inv = LD(g, obn + tid, F) * rsqrtf(LD(v, obn + tid, F) + BN_EPS);
        sA[tid] = inv;
        sB[tid] = LD(be, obn + tid, F) - LD(m, obn + tid, F) * inv;
    }
    __syncthreads();
    int o = tid >> 3, wsub = tid & 7;
    float xb = sxb[o], aa = sA[o], bb = sB[o];
    for (int w = wsub; w < W1O; w += 8){
        float a = xb;
        #pragma unroll
        for (int k = 0; k < 16; k++)
            a += sP[(k*26 + stg[w + k])*32 + o];
        g_c1o[(b*32 + o)*C1S + w] = fmaxf(a * aa + bb, 0.f);
    }
}

// ---------------- conv2/conv3: register-tiled f32, [ch][w] layouts ----------------
// Block: 64 w x 32 o. 256 thr = 16 wg (4 w each) x 16 og (2 o each).
// sel 0: g_c1o -> g_c2o. sel 1: g_c2o -> atomicMax g_xcm.

__global__ __launch_bounds__(256) void k_conv2(
    int sel, int Wvalid, int Wout, int tiles, int inStride,
    const void* Wt,
    const void* bias, const void* g, const void* be,
    const void* m, const void* v, int obn)
{
    const int F = g_isf32;
    const float* in = (sel == 0) ? g_c1o : g_c2o;
    __shared__ float sW[8][32][36];      // one k-half, padded: 36.9 KB
    __shared__ float sIn[32][84];        // [c][80 w tile], padded: 10.8 KB
    __shared__ float sA[32], sB[32];
    int tid = threadIdx.x;
    int b = blockIdx.x / tiles;
    int tile = blockIdx.x - b*tiles;
    int w0t = tile * 64;

    // stage input tile: global reads are w-contiguous (coalesced)
    for (int i = tid; i < 32*80; i += 256){
        int c = i / 80, wl = i - c*80;
        int wg_ = w0t + wl;
        sIn[c][wl] = (wg_ < Wvalid) ? in[(b*32 + c)*inStride + wg_] : 0.f;
    }
    if (tid < 32){
        float inv = LD(g, obn + tid, F) * rsqrtf(LD(v, obn + tid, F) + BN_EPS);
        sA[tid] = inv;
        sB[tid] = LD(be, obn + tid, F) + (LD(bias, tid, F) - LD(m, obn + tid, F)) * inv;
    }

    int wg = tid & 15, og = tid >> 4;
    int w0 = w0t + wg*4;
    float acc[8];
    #pragma unroll
    for (int j = 0; j < 8; j++) acc[j] = 0.f;

    for (int kh = 0; kh < 2; kh++){
        __syncthreads();                 // sIn done (kh=0) / sW reads done (kh=1)
        // stage weight half: global reads linear in k8 (coalesced bursts)
        for (int i = tid; i < 8192; i += 256){
            int o = i >> 8, c = (i >> 3) & 31, k8 = i & 7;
            sW[k8][c][o] = LD(Wt, o*512 + c*16 + kh*8 + k8, F);
        }
        __syncthreads();
        for (int c = 0; c < 32; c++){
            const float4* pw = (const float4*)&sIn[c][kh*8 + wg*4];   // 16B aligned
            float4 q0 = pw[0], q1 = pw[1], q2 = pw[2];
            float r[12] = {q0.x,q0.y,q0.z,q0.w, q1.x,q1.y,q1.z,q1.w,
                           q2.x,q2.y,q2.z,q2.w};
            #pragma unroll
            for (int k8 = 0; k8 < 8; k8++){
                const float2 wv = *(const float2*)&sW[k8][c][og*2];   // 8B aligned, 4 addrs/wave
                #pragma unroll
                for (int ww = 0; ww < 4; ww++){
                    acc[ww*2 + 0] += r[ww + k8] * wv.x;
                    acc[ww*2 + 1] += r[ww + k8] * wv.y;
                }
            }
        }
    }

    int o0 = og*2;
    if (sel == 0){
        #pragma unroll
        for (int oo = 0; oo < 2; oo++){
            int o = o0 + oo;
            float y[4];
            #pragma unroll
            for (int ww = 0; ww < 4; ww++)
                y[ww] = fmaxf(acc[ww*2 + oo] * sA[o] + sB[o], 0.f);
            float* dst = &g_c2o[(b*32 + o)*C2S + w0];
            if (w0 + 3 < Wout){
                *(float4*)dst = make_float4(y[0], y[1], y[2], y[3]);  // 16B aligned (C2S%4==0, w0%4==0)
            } else {
                #pragma unroll
                for (int ww = 0; ww < 4; ww++)
                    if (w0 + ww < Wout) dst[ww] = y[ww];
            }
        }
    } else {
        #pragma unroll
        for (int oo = 0; oo < 2; oo++){
            int o = o0 + oo;
            float mx = 0.f;
            bool any = false;
            #pragma unroll
            for (int ww = 0; ww < 4; ww++){
                if (w0 + ww < Wout){
                    float yv = fmaxf(acc[ww*2 + oo] * sA[o] + sB[o], 0.f);
                    mx = fmaxf(mx, yv);
                    any = true;
                }
            }
            if (any) atomicMax((int*)&g_xcm[b*32 + o], __float_as_int(mx));
        }
    }
}

// ---------------- FC tail ----------------

__global__ void k_xcf(const void* W, const void* bias,
                      const void* g, const void* be, const void* m, const void* v){
    const int F = g_isf32;
    __shared__ float sp[32];
    int b = blockIdx.x, j = threadIdx.x;
    if (j < 32) sp[j] = g_xcm[b*32 + j];
    __syncthreads();
    float a = LD(bias, j, F);
    #pragma unroll
    for (int i = 0; i < 32; i++) a += sp[i] * LD(W, i*128 + j, F);
    float inv = LD(g, j, F) * rsqrtf(LD(v, j, F) + BN_EPS);
    a = (a - LD(m, j, F)) * inv + LD(be, j, F);
    g_xcf[b*128 + j] = fmaxf(a, 0.f);
}

__global__ __launch_bounds__(256) void k_fc1(const void* W, const void* bias){
    const int F = g_isf32;
    __shared__ float sz[256];
    int b = blockIdx.x >> 2;
    int j = ((blockIdx.x & 3) << 8) + threadIdx.x;
    int t = threadIdx.x;
    sz[t] = (t < 128) ? g_xd[b*128 + t] : g_xcf[b*128 + (t - 128)];
    __syncthreads();
    float a = LD(bias, j, F);
    for (int i = 0; i < 256; i++) a += sz[i] * LD(W, i*1024 + j, F);
    g_z1[b*1024 + j] = fmaxf(a, 0.f);
}

__global__ __launch_bounds__(256) void k_fc2(const void* W, const void* bias){
    const int F = g_isf32;
    __shared__ float sz[1024];
    int b = blockIdx.x, t = threadIdx.x;
    for (int i = t; i < 1024; i += 256) sz[i] = g_z1[b*1024 + i];
    __syncthreads();
    float a = LD(bias, t, F);
    for (int i = 0; i < 1024; i++) a += sz[i] * LD(W, i*256 + t, F);
    g_z2[b*256 + t] = fmaxf(a, 0.f);
}

__global__ void k_out(const void* W, const void* bias, void* out){
    const int F = g_isf32;
    __shared__ float red[256];
    int b = blockIdx.x, t = threadIdx.x;
    red[t] = g_z2[b*256 + t] * LD(W, t, F);
    __syncthreads();
    for (int s = 128; s > 0; s >>= 1){
        if (t < s) red[t] += red[t + s];
        __syncthreads();
    }
    if (t == 0){
        float r = red[0] + LD(bias, 0, F);
        if (F) ((float*)out)[b] = r;
        else   ((bf16*)out)[b] = __float2bfloat16(r);
    }
}

// ---------------- launch ----------------

extern "C" void kernel_launch(void* const* d_in, const int* in_sizes, int n_in,
                              void* d_out, int out_size, void* d_ws, size_t ws_size,
                              hipStream_t stream)
{
    (void)in_sizes; (void)n_in; (void)out_size; (void)d_ws; (void)ws_size;
    const void* x      = d_in[0];
    const int*  ei     = (const int*)d_in[1];
    const int*  batch  = (const int*)d_in[2];
    const int*  target = (const int*)d_in[3];
    const void* g1W1 = d_in[4];  const void* g1b1 = d_in[5];
    const void* g1W2 = d_in[6];  const void* g1b2 = d_in[7];
    const void* gW1  = d_in[8];  const void* gb1  = d_in[9];
    const void* gW2  = d_in[10]; const void* gb2  = d_in[11];
    const void* bng  = d_in[12]; const void* bnb  = d_in[13];
    const void* bnm  = d_in[14]; const void* bnv  = d_in[15];
    const void* fcxdW = d_in[16]; const void* fcxdb = d_in[17];
    const void* embed = d_in[18];
    const void* c1W = d_in[19]; const void* c1b = d_in[20];
    const void* c2W = d_in[21]; const void* c2b = d_in[22];
    const void* c3W = d_in[23]; const void* c3b = d_in[24];
    const void* cbng = d_in[25]; const void* cbnb = d_in[26];
    const void* cbnm = d_in[27]; const void* cbnv = d_in[28];
    const void* fcxcW = d_in[29]; const void* fcxcb = d_in[30];
    const void* bnfcg = d_in[31]; const void* bnfcb = d_in[32];
    const void* bnfcm = d_in[33]; const void* bnfcv = d_in[34];
    const void* fc1W = d_in[35]; const void* fc1b = d_in[36];
    const void* fc2W = d_in[37]; const void* fc2b = d_in[38];
    const void* outW = d_in[39]; const void* outb = d_in[40];

    k_dtype<<<1, 64, 0, stream>>>(x);

    // ---- GIN layer 1 (projected scatter) ----
    k_proj78<<<N_NODES/8, 256, 0, stream>>>(x, g1W1);
    k_zero_agg<<<N_NODES*32/256, 256, 0, stream>>>();
    k_zero_misc<<<NB*32/256, 256, 0, stream>>>();
    k_scatter32<<<(N_EDGES*32)/256, 256, 0, stream>>>(ei);
    k_gin1b<<<N_NODES/8, 256, 0, stream>>>(g1b1, g1W2, g1b2, bng, bnb, bnm, bnv);
    // ---- GIN layers 2..5 ----
    for (int l = 0; l < 4; l++){
        k_zero_agg<<<N_NODES*32/256, 256, 0, stream>>>();
        k_scatter32<<<(N_EDGES*32)/256, 256, 0, stream>>>(ei);
        k_gin32L<<<N_NODES/8, 256, 0, stream>>>(gW1, gb1, gW2, gb2,
                                                bng, bnb, bnm, bnv, l);
    }
    // ---- pool + xd ----
    k_pool<<<(N_NODES*32)/256, 256, 0, stream>>>(batch);
    k_xd<<<NB, 128, 0, stream>>>(fcxdW, fcxdb);
    // ---- conv1 prep ----
    k_P<<<(16*26*32 + 255)/256, 256, 0, stream>>>(embed, c1W);
    k_wsum<<<16, 256, 0, stream>>>(c1W);
    k_xdbias<<<32, 256, 0, stream>>>(c1b);
    // ---- conv chain ----
    k_conv1L<<<NB, 256, 0, stream>>>(target, cbng, cbnb, cbnm, cbnv, 0);
    k_conv2<<<NB*16, 256, 0, stream>>>(0, W1O, W2O, 16, C1S, c2W,
                                       c2b, cbng, cbnb, cbnm, cbnv, 32);
    k_conv2<<<NB*15, 256, 0, stream>>>(1, W2O, W3O, 15, C2S, c3W,
                                       c3b, cbng, cbnb, cbnm, cbnv, 64);
    // ---- FC tail ----
    k_xcf<<<NB, 128, 0, stream>>>(fcxcW, fcxcb, bnfcg, bnfcb, bnfcm, bnfcv);
    k_fc1<<<NB*4, 256, 0, stream>>>(fc1W, fc1b);
    k_fc2<<<NB, 256, 0, stream>>>(fc2W, fc2b);
    k_out<<<NB, 256, 0, stream>>>(outW, outb, d_out);
}

// Round 7
// 755.888 us; speedup vs baseline: 2.8831x; 1.5024x over previous
//
#include <hip/hip_runtime.h>
#include <hip/hip_bf16.h>

typedef __hip_bfloat16 bf16;
__device__ __forceinline__ float b2f(bf16 v){ return __bfloat162float(v); }

typedef __attribute__((ext_vector_type(8))) short s8v;
typedef __attribute__((ext_vector_type(4))) float f4v;

#define N_NODES 16384
#define N_EDGES 65536
#define NB 256
#define LSEQ 1000
#define BN_EPS 1e-5f
#define W1O 985
#define W2O 970
#define W3O 955
#define C1S 988          // g_c1o row stride (floats), layout [b][32 ch][C1S]
#define C2S 976          // g_c2o row stride (floats), layout [b][32 ch][C2S]

// ---- dtype flag: 1 if float inputs are f32, 0 if bf16 (measured: f32 on this harness) ----
__device__ int g_isf32;

__device__ __forceinline__ float LD(const void* p, int i, int f){
    return f ? ((const float*)p)[i] : b2f(((const bf16*)p)[i]);
}

// f32 -> bf16 bits, round-to-nearest-even
__device__ __forceinline__ unsigned short f2b(float x){
    unsigned u = __float_as_uint(x);
    return (unsigned short)((u + 0x7FFFu + ((u >> 16) & 1u)) >> 16);
}
__device__ __forceinline__ float bb2f(unsigned short h){
    return __uint_as_float(((unsigned)h) << 16);
}

__global__ void k_dtype(const void* x){
    if (threadIdx.x != 0 || blockIdx.x != 0) return;
    const unsigned short* u = (const unsigned short*)x;
    int insane = 0;
    for (int i = 0; i < 512; i++){
        unsigned short h = u[i];
        int ex = (h >> 7) & 0xFF;
        if (!(h == 0 || (ex >= 96 && ex <= 142))) insane++;
    }
    g_isf32 = (insane > 50) ? 1 : 0;
}

// ---- intermediates in device globals ----
__device__ float g_hA[N_NODES*32];
__device__ float g_agg[N_NODES*32];
__device__ float g_pooled[NB*32];
__device__ float g_xd[NB*128];
__device__ float g_P[16*26*32];
__device__ float g_wsum[32*128];
__device__ float g_xdb[NB*32];
__device__ float g_xcm[NB*32];
__device__ float g_xcf[NB*128];
__device__ float g_z1[NB*1024];
__device__ float g_z2[NB*256];
__device__ float g_c1o[NB*32*C1S];   // 32.4 MB, [b][o][w]
__device__ float g_c2o[NB*32*C2S];   // 32.0 MB, [b][o][w]

__global__ void k_zero_agg(){ g_agg[blockIdx.x*256 + threadIdx.x] = 0.f; }
__global__ void k_zero_misc(){
    int i = blockIdx.x*256 + threadIdx.x;
    g_pooled[i] = 0.f;
    g_xcm[i] = 0.f;
}

// ---------------- GIN branch ----------------

__global__ __launch_bounds__(256) void k_proj78(const void* x, const void* W1)
{
    const int F = g_isf32;
    __shared__ float sW1[78*32];
    __shared__ float sx[8][78];
    int tid = threadIdx.x;
    for (int i = tid; i < 78*32; i += 256) sW1[i] = LD(W1, i, F);
    int nodeBase = blockIdx.x * 8;
    for (int i = tid; i < 8*78; i += 256){
        int ln = i / 78, f = i - ln*78;
        sx[ln][f] = LD(x, (nodeBase + ln)*78 + f, F);
    }
    __syncthreads();
    int ln = tid >> 5, j = tid & 31;
    float a = 0.f;
    #pragma unroll 6
    for (int i = 0; i < 78; i++) a += sx[ln][i] * sW1[i*32 + j];
    g_hA[(nodeBase + ln)*32 + j] = a;
}

__global__ void k_scatter32(const int* __restrict__ ei){
    int idx = blockIdx.x*256 + threadIdx.x;
    int e = idx >> 5, f = idx & 31;
    atomicAdd(&g_agg[ei[N_EDGES + e]*32 + f], g_hA[ei[e]*32 + f]);
}

__global__ __launch_bounds__(256) void k_gin1b(
    const void* b1, const void* W2, const void* b2,
    const void* bng, const void* bnb, const void* bnm, const void* bnv)
{
    const int F = g_isf32;
    __shared__ float sW2[32*32];
    __shared__ float sb1[32], sb2[32], sA[32], sB[32];
    __shared__ float st[8][32];
    int tid = threadIdx.x;
    for (int i = tid; i < 1024; i += 256) sW2[i] = LD(W2, i, F);
    if (tid < 32){
        sb1[tid] = LD(b1, tid, F); sb2[tid] = LD(b2, tid, F);
        float inv = LD(bng, tid, F) * rsqrtf(LD(bnv, tid, F) + BN_EPS);
        sA[tid] = inv;
        sB[tid] = LD(bnb, tid, F) - LD(bnm, tid, F) * inv;
    }
    __syncthreads();
    int ln = tid >> 5, j = tid & 31;
    int n = blockIdx.x*8 + ln;
    st[ln][j] = fmaxf(g_hA[n*32 + j] + g_agg[n*32 + j] + sb1[j], 0.f);
    __syncthreads();
    float t2 = sb2[j];
    #pragma unroll
    for (int i = 0; i < 32; i++) t2 += st[ln][i] * sW2[i*32 + j];
    t2 = fmaxf(t2, 0.f);
    g_hA[n*32 + j] = t2 * sA[j] + sB[j];
}

__global__ __launch_bounds__(256) void k_gin32L(
    const void* W1, const void* b1, const void* W2, const void* b2,
    const void* bng, const void* bnb, const void* bnm, const void* bnv, int l)
{
    const int F = g_isf32;
    const int oW = l*1024, ob = l*32, obn = (l+1)*32;
    __shared__ float sW1[32*32], sW2[32*32];
    __shared__ float sb1[32], sb2[32], sA[32], sB[32];
    __shared__ float sh[8][32], st[8][32];
    int tid = threadIdx.x;
    for (int i = tid; i < 1024; i += 256){ sW1[i] = LD(W1, oW + i, F); sW2[i] = LD(W2, oW + i, F); }
    if (tid < 32){
        sb1[tid] = LD(b1, ob + tid, F); sb2[tid] = LD(b2, ob + tid, F);
        float inv = LD(bng, obn + tid, F) * rsqrtf(LD(bnv, obn + tid, F) + BN_EPS);
        sA[tid] = inv;
        sB[tid] = LD(bnb, obn + tid, F) - LD(bnm, obn + tid, F) * inv;
    }
    int ln = tid >> 5, j = tid & 31;
    int n = blockIdx.x*8 + ln;
    sh[ln][j] = g_hA[n*32 + j] + g_agg[n*32 + j];
    __syncthreads();
    float t1 = sb1[j];
    #pragma unroll
    for (int i = 0; i < 32; i++) t1 += sh[ln][i] * sW1[i*32 + j];
    st[ln][j] = fmaxf(t1, 0.f);
    __syncthreads();
    float t2 = sb2[j];
    #pragma unroll
    for (int i = 0; i < 32; i++) t2 += st[ln][i] * sW2[i*32 + j];
    t2 = fmaxf(t2, 0.f);
    g_hA[n*32 + j] = t2 * sA[j] + sB[j];
}

__global__ void k_pool(const int* __restrict__ batch){
    int idx = blockIdx.x*256 + threadIdx.x;
    int n = idx >> 5;
    atomicAdd(&g_pooled[batch[n]*32 + (idx & 31)], g_hA[idx]);
}

__global__ void k_xd(const void* W, const void* bias){
    const int F = g_isf32;
    __shared__ float sp[32];
    int b = blockIdx.x, j = threadIdx.x;
    if (j < 32) sp[j] = g_pooled[b*32 + j];
    __syncthreads();
    float a = LD(bias, j, F);
    #pragma unroll
    for (int i = 0; i < 32; i++) a += sp[i] * LD(W, i*128 + j, F);
    g_xd[b*128 + j] = fmaxf(a, 0.f);
}

// ---------------- conv1 via 26-row embedding table ----------------

__global__ void k_P(const void* embed, const void* c1W){
    const int F = g_isf32;
    int idx = blockIdx.x*256 + threadIdx.x;
    if (idx >= 16*26*32) return;
    int o = idx & 31;
    int t = (idx >> 5) % 26;
    int k = idx / (32*26);
    float a = 0.f;
    for (int c = 0; c < 128; c++)
        a += LD(embed, t*128 + c, F) * LD(c1W, o*4096 + c*16 + k, F);
    g_P[(k*26 + t)*32 + o] = a;
}

__global__ void k_wsum(const void* c1W){
    const int F = g_isf32;
    int idx = blockIdx.x*256 + threadIdx.x;
    int o = idx >> 7, c = idx & 127;
    float a = 0.f;
    #pragma unroll
    for (int k = 0; k < 16; k++) a += LD(c1W, o*4096 + (128 + c)*16 + k, F);
    g_wsum[o*128 + c] = a;
}

__global__ void k_xdbias(const void* c1b){
    const int F = g_isf32;
    int idx = blockIdx.x*256 + threadIdx.x;
    int b = idx >> 5, o = idx & 31;
    float a = LD(c1b, o, F);
    for (int c = 0; c < 128; c++) a += g_xd[b*128 + c] * g_wsum[o*128 + c];
    g_xdb[idx] = a;
}

// writes [b][o][w] layout (stride C1S)
__global__ __launch_bounds__(256) void k_conv1L(
    const int* __restrict__ target,
    const void* g, const void* be, const void* m, const void* v, int obn)
{
    const int F = g_isf32;
    __shared__ float sP[16*26*32];
    __shared__ int   stg[LSEQ];
    __shared__ float sxb[32], sA[32], sB[32];
    int b = blockIdx.x, tid = threadIdx.x;
    for (int i = tid; i < 16*26*32; i += 256) sP[i] = g_P[i];
    for (int i = tid; i < LSEQ; i += 256) stg[i] = target[b*LSEQ + i];
    if (tid < 32){
        sxb[tid] = g_xdb[b*32 + tid];
        float inv = LD(g, obn + tid, F) * rsqrtf(LD(v, obn + tid, F) + BN_EPS);
        sA[tid] = inv;
        sB[tid] = LD(be, obn + tid, F) - LD(m, obn + tid, F) * inv;
    }
    __syncthreads();
    int o = tid >> 3, wsub = tid & 7;
    float xb = sxb[o], aa = sA[o], bb = sB[o];
    for (int w = wsub; w < W1O; w += 8){
        float a = xb;
        #pragma unroll
        for (int k = 0; k < 16; k++)
            a += sP[(k*26 + stg[w + k])*32 + o];
        g_c1o[(b*32 + o)*C1S + w] = fmaxf(a * aa + bb, 0.f);
    }
}

// ---------------- conv2/conv3 via MFMA, double-bf16 split (f32-accurate) ------
// Per tap kt: C[w][o] += In[w+kt][c]*W[c][o]; each f32 split hi/lo bf16,
// C += Ah*Bh + Ah*Bl + Al*Bh (3 MFMAs, Al*Bl ~2^-18 dropped).
// Tile: 128 w x 32 o per block; 4 waves = 2 w-halves x 2 o-halves,
// each wave 64 w x 16 o = 4 m-tiles x 1 n-frag. Taps in 2 passes of 8
// (weights restaged between passes to fit LDS).
// A-frag: A[m=lane&15][k=quad*8+j] = sA*[w0+m+kt][quad*8+j]   (ds_read_b128)
// B-frag: B[k=quad*8+j][n=lane&15] = sB*[kt][o][quad*8+j]
// C/D   : col(o)=lane&15, row(w)=quad*4+reg                    (m89/m91)

#define CT_W 128
#define CT_R 144     // 128 + 15 halo, padded
#define CPAD 40      // c-row pad: 80 B = 16B-aligned rows, 2-way bank alias (free)

__global__ __launch_bounds__(256) void k_cmfma(
    int sel, int Wvalid, int Wout, int inStride,
    const void* Wt, const void* bias, const void* g, const void* be,
    const void* m, const void* v, int obn)
{
    const int F = g_isf32;
    const float* in = (sel == 0) ? g_c1o : g_c2o;
    __shared__ __attribute__((aligned(16))) unsigned short sAh[CT_R*CPAD]; // 11520 B
    __shared__ __attribute__((aligned(16))) unsigned short sAl[CT_R*CPAD]; // 11520 B
    __shared__ __attribute__((aligned(16))) unsigned short sBh[8*32*CPAD]; // 20480 B
    __shared__ __attribute__((aligned(16))) unsigned short sBl[8*32*CPAD]; // 20480 B
    __shared__ float sSc[32], sOf[32];
    int tid = threadIdx.x;
    int b = blockIdx.x >> 3;
    int tile = blockIdx.x & 7;
    int wbase = tile * CT_W;

    // stage input tile (hi/lo split); coalesced along w per channel row
    for (int c = 0; c < 32; c++){
        const float* src = in + (b*32 + c)*inStride;
        if (tid < CT_R){
            int wg_ = wbase + tid;
            float xv = (wg_ < Wvalid) ? src[wg_] : 0.f;
            unsigned short h = f2b(xv);
            sAh[tid*CPAD + c] = h;
            sAl[tid*CPAD + c] = f2b(xv - bb2f(h));
        }
    }
    if (tid < 32){
        float inv = LD(g, obn + tid, F) * rsqrtf(LD(v, obn + tid, F) + BN_EPS);
        sSc[tid] = inv;
        sOf[tid] = LD(be, obn + tid, F) + (LD(bias, tid, F) - LD(m, obn + tid, F)) * inv;
    }

    int lane = tid & 63;
    int wv = tid >> 6;
    int ml = lane & 15, quad = lane >> 4;
    int wgrp = wv & 1;           // w-half: 0 -> w 0..63, 1 -> 64..127
    int ogrp = wv >> 1;          // o-half: o = ml + ogrp*16

    f4v acc[4];
    #pragma unroll
    for (int mt = 0; mt < 4; mt++) acc[mt] = (f4v){0.f, 0.f, 0.f, 0.f};

    for (int kh = 0; kh < 2; kh++){
        __syncthreads();         // sA visible (kh=0) / pass-0 B reads done (kh=1)
        // stage 8-tap weight block, hi/lo split; global reads contiguous in kt8
        for (int i = tid; i < 8192; i += 256){
            int kt8 = i & 7, c = (i >> 3) & 31, o = i >> 8;
            float wv_ = LD(Wt, o*512 + c*16 + kh*8 + kt8, F);
            unsigned short h = f2b(wv_);
            sBh[(kt8*32 + o)*CPAD + c] = h;
            sBl[(kt8*32 + o)*CPAD + c] = f2b(wv_ - bb2f(h));
        }
        __syncthreads();
        for (int kt = 0; kt < 8; kt++){
            int ktg = kh*8 + kt;
            const int bidx = (kt*32 + ogrp*16 + ml)*CPAD + quad*8;
            s8v bh = *(const s8v*)&sBh[bidx];
            s8v bl = *(const s8v*)&sBl[bidx];
            #pragma unroll
            for (int mt = 0; mt < 4; mt++){
                int row = wgrp*64 + mt*16 + ml + ktg;
                const int aidx = row*CPAD + quad*8;
                s8v ah = *(const s8v*)&sAh[aidx];
                s8v al = *(const s8v*)&sAl[aidx];
                acc[mt] = __builtin_amdgcn_mfma_f32_16x16x32_bf16(ah, bh, acc[mt], 0, 0, 0);
                acc[mt] = __builtin_amdgcn_mfma_f32_16x16x32_bf16(ah, bl, acc[mt], 0, 0, 0);
                acc[mt] = __builtin_amdgcn_mfma_f32_16x16x32_bf16(al, bh, acc[mt], 0, 0, 0);
            }
        }
    }

    int o = ogrp*16 + ml;
    float sc = sSc[o], of = sOf[o];
    #pragma unroll
    for (int mt = 0; mt < 4; mt++){
        int w0 = wbase + wgrp*64 + mt*16 + quad*4;
        f4v a = acc[mt];
        float y0 = fmaxf(a.x*sc + of, 0.f);
        float y1 = fmaxf(a.y*sc + of, 0.f);
        float y2 = fmaxf(a.z*sc + of, 0.f);
        float y3 = fmaxf(a.w*sc + of, 0.f);
        if (sel == 0){
            float* dst = &g_c2o[(b*32 + o)*C2S + w0];
            if (w0 + 3 < Wout){
                *(float4*)dst = make_float4(y0, y1, y2, y3);
            } else if (w0 < Wout){
                dst[0] = y0;
                if (w0+1 < Wout) dst[1] = y1;
                if (w0+2 < Wout) dst[2] = y2;
                if (w0+3 < Wout) dst[3] = y3;
            }
        } else {
            if (w0 < Wout){
                float mx = y0;
                if (w0+1 < Wout) mx = fmaxf(mx, y1);
                if (w0+2 < Wout) mx = fmaxf(mx, y2);
                if (w0+3 < Wout) mx = fmaxf(mx, y3);
                atomicMax((int*)&g_xcm[b*32 + o], __float_as_int(mx));
            }
        }
    }
}

// ---------------- FC tail ----------------

__global__ void k_xcf(const void* W, const void* bias,
                      const void* g, const void* be, const void* m, const void* v){
    const int F = g_isf32;
    __shared__ float sp[32];
    int b = blockIdx.x, j = threadIdx.x;
    if (j < 32) sp[j] = g_xcm[b*32 + j];
    __syncthreads();
    float a = LD(bias, j, F);
    #pragma unroll
    for (int i = 0; i < 32; i++) a += sp[i] * LD(W, i*128 + j, F);
    float inv = LD(g, j, F) * rsqrtf(LD(v, j, F) + BN_EPS);
    a = (a - LD(m, j, F)) * inv + LD(be, j, F);
    g_xcf[b*128 + j] = fmaxf(a, 0.f);
}

__global__ __launch_bounds__(256) void k_fc1(const void* W, const void* bias){
    const int F = g_isf32;
    __shared__ float sz[256];
    int b = blockIdx.x >> 2;
    int j = ((blockIdx.x & 3) << 8) + threadIdx.x;
    int t = threadIdx.x;
    sz[t] = (t < 128) ? g_xd[b*128 + t] : g_xcf[b*128 + (t - 128)];
    __syncthreads();
    float a = LD(bias, j, F);
    for (int i = 0; i < 256; i++) a += sz[i] * LD(W, i*1024 + j, F);
    g_z1[b*1024 + j] = fmaxf(a, 0.f);
}

__global__ __launch_bounds__(256) void k_fc2(const void* W, const void* bias){
    const int F = g_isf32;
    __shared__ float sz[1024];
    int b = blockIdx.x, t = threadIdx.x;
    for (int i = t; i < 1024; i += 256) sz[i] = g_z1[b*1024 + i];
    __syncthreads();
    float a = LD(bias, t, F);
    for (int i = 0; i < 1024; i++) a += sz[i] * LD(W, i*256 + t, F);
    g_z2[b*256 + t] = fmaxf(a, 0.f);
}

__global__ void k_out(const void* W, const void* bias, void* out){
    const int F = g_isf32;
    __shared__ float red[256];
    int b = blockIdx.x, t = threadIdx.x;
    red[t] = g_z2[b*256 + t] * LD(W, t, F);
    __syncthreads();
    for (int s = 128; s > 0; s >>= 1){
        if (t < s) red[t] += red[t + s];
        __syncthreads();
    }
    if (t == 0){
        float r = red[0] + LD(bias, 0, F);
        if (F) ((float*)out)[b] = r;
        else   ((bf16*)out)[b] = __float2bfloat16(r);
    }
}

// ---------------- launch ----------------

extern "C" void kernel_launch(void* const* d_in, const int* in_sizes, int n_in,
                              void* d_out, int out_size, void* d_ws, size_t ws_size,
                              hipStream_t stream)
{
    (void)in_sizes; (void)n_in; (void)out_size; (void)d_ws; (void)ws_size;
    const void* x      = d_in[0];
    const int*  ei     = (const int*)d_in[1];
    const int*  batch  = (const int*)d_in[2];
    const int*  target = (const int*)d_in[3];
    const void* g1W1 = d_in[4];  const void* g1b1 = d_in[5];
    const void* g1W2 = d_in[6];  const void* g1b2 = d_in[7];
    const void* gW1  = d_in[8];  const void* gb1  = d_in[9];
    const void* gW2  = d_in[10]; const void* gb2  = d_in[11];
    const void* bng  = d_in[12]; const void* bnb  = d_in[13];
    const void* bnm  = d_in[14]; const void* bnv  = d_in[15];
    const void* fcxdW = d_in[16]; const void* fcxdb = d_in[17];
    const void* embed = d_in[18];
    const void* c1W = d_in[19]; const void* c1b = d_in[20];
    const void* c2W = d_in[21]; const void* c2b = d_in[22];
    const void* c3W = d_in[23]; const void* c3b = d_in[24];
    const void* cbng = d_in[25]; const void* cbnb = d_in[26];
    const void* cbnm = d_in[27]; const void* cbnv = d_in[28];
    const void* fcxcW = d_in[29]; const void* fcxcb = d_in[30];
    const void* bnfcg = d_in[31]; const void* bnfcb = d_in[32];
    const void* bnfcm = d_in[33]; const void* bnfcv = d_in[34];
    const void* fc1W = d_in[35]; const void* fc1b = d_in[36];
    const void* fc2W = d_in[37]; const void* fc2b = d_in[38];
    const void* outW = d_in[39]; const void* outb = d_in[40];

    k_dtype<<<1, 64, 0, stream>>>(x);

    // ---- GIN layer 1 (projected scatter) ----
    k_proj78<<<N_NODES/8, 256, 0, stream>>>(x, g1W1);
    k_zero_agg<<<N_NODES*32/256, 256, 0, stream>>>();
    k_zero_misc<<<NB*32/256, 256, 0, stream>>>();
    k_scatter32<<<(N_EDGES*32)/256, 256, 0, stream>>>(ei);
    k_gin1b<<<N_NODES/8, 256, 0, stream>>>(g1b1, g1W2, g1b2, bng, bnb, bnm, bnv);
    // ---- GIN layers 2..5 ----
    for (int l = 0; l < 4; l++){
        k_zero_agg<<<N_NODES*32/256, 256, 0, stream>>>();
        k_scatter32<<<(N_EDGES*32)/256, 256, 0, stream>>>(ei);
        k_gin32L<<<N_NODES/8, 256, 0, stream>>>(gW1, gb1, gW2, gb2,
                                                bng, bnb, bnm, bnv, l);
    }
    // ---- pool + xd ----
    k_pool<<<(N_NODES*32)/256, 256, 0, stream>>>(batch);
    k_xd<<<NB, 128, 0, stream>>>(fcxdW, fcxdb);
    // ---- conv1 prep ----
    k_P<<<(16*26*32 + 255)/256, 256, 0, stream>>>(embed, c1W);
    k_wsum<<<16, 256, 0, stream>>>(c1W);
    k_xdbias<<<32, 256, 0, stream>>>(c1b);
    // ---- conv chain ----
    k_conv1L<<<NB, 256, 0, stream>>>(target, cbng, cbnb, cbnm, cbnv, 0);
    k_cmfma<<<NB*8, 256, 0, stream>>>(0, W1O, W2O, C1S, c2W,
                                      c2b, cbng, cbnb, cbnm, cbnv, 32);
    k_cmfma<<<NB*8, 256, 0, stream>>>(1, W2O, W3O, C2S, c3W,
                                      c3b, cbng, cbnb, cbnm, cbnv, 64);
    // ---- FC tail ----
    k_xcf<<<NB, 128, 0, stream>>>(fcxcW, fcxcb, bnfcg, bnfcb, bnfcm, bnfcv);
    k_fc1<<<NB*4, 256, 0, stream>>>(fc1W, fc1b);
    k_fc2<<<NB, 256, 0, stream>>>(fc2W, fc2b);
    k_out<<<NB, 256, 0, stream>>>(outW, outb, d_out);
}

// Round 9
// 736.304 us; speedup vs baseline: 2.9598x; 1.0266x over previous
//
#include <hip/hip_runtime.h>
#include <hip/hip_bf16.h>

typedef __hip_bfloat16 bf16;
__device__ __forceinline__ float b2f(bf16 v){ return __bfloat162float(v); }

typedef __attribute__((ext_vector_type(8))) short s8v;
typedef __attribute__((ext_vector_type(4))) float f4v;

#define N_NODES 16384
#define N_EDGES 65536
#define NB 256
#define LSEQ 1000
#define BN_EPS 1e-5f
#define W1O 985
#define W2O 970
#define W3O 955
#define C1S 988          // g_c1o row stride (floats), layout [b][32 ch][C1S]
#define C2S 976          // g_c2o row stride (floats), layout [b][32 ch][C2S]

// ---- dtype flag: 1 if float inputs are f32, 0 if bf16 (measured: f32 on this harness) ----
__device__ int g_isf32;

__device__ __forceinline__ float LD(const void* p, int i, int f){
    return f ? ((const float*)p)[i] : b2f(((const bf16*)p)[i]);
}

// f32 -> bf16 bits, round-to-nearest-even
__device__ __forceinline__ unsigned short f2b(float x){
    unsigned u = __float_as_uint(x);
    return (unsigned short)((u + 0x7FFFu + ((u >> 16) & 1u)) >> 16);
}
__device__ __forceinline__ float bb2f(unsigned short h){
    return __uint_as_float(((unsigned)h) << 16);
}

__global__ void k_dtype(const void* x){
    if (threadIdx.x != 0 || blockIdx.x != 0) return;
    const unsigned short* u = (const unsigned short*)x;
    int insane = 0;
    for (int i = 0; i < 512; i++){
        unsigned short h = u[i];
        int ex = (h >> 7) & 0xFF;
        if (!(h == 0 || (ex >= 96 && ex <= 142))) insane++;
    }
    g_isf32 = (insane > 50) ? 1 : 0;
}

// ---- intermediates in device globals ----
__device__ float g_hA[N_NODES*32];
__device__ float g_agg[N_NODES*32];
__device__ float g_pooled[NB*32];
__device__ float g_xd[NB*128];
__device__ float g_P[16*26*32];
__device__ float g_wsum[32*128];
__device__ float g_xdb[NB*32];
__device__ float g_xcm[NB*32];
__device__ float g_xcf[NB*128];
__device__ float g_z1[NB*1024];
__device__ float g_z2[NB*256];
__device__ float g_c1o[NB*32*C1S];   // 32.4 MB, [b][o][w]
__device__ float g_c2o[NB*32*C2S];   // 32.0 MB, [b][o][w]

__global__ void k_zero_agg(){ g_agg[blockIdx.x*256 + threadIdx.x] = 0.f; }
__global__ void k_zero_misc(){
    int i = blockIdx.x*256 + threadIdx.x;
    g_pooled[i] = 0.f;
    g_xcm[i] = 0.f;
}

// ---------------- GIN branch ----------------

__global__ __launch_bounds__(256) void k_proj78(const void* x, const void* W1)
{
    const int F = g_isf32;
    __shared__ float sW1[78*32];
    __shared__ float sx[8][78];
    int tid = threadIdx.x;
    for (int i = tid; i < 78*32; i += 256) sW1[i] = LD(W1, i, F);
    int nodeBase = blockIdx.x * 8;
    for (int i = tid; i < 8*78; i += 256){
        int ln = i / 78, f = i - ln*78;
        sx[ln][f] = LD(x, (nodeBase + ln)*78 + f, F);
    }
    __syncthreads();
    int ln = tid >> 5, j = tid & 31;
    float a = 0.f;
    #pragma unroll 6
    for (int i = 0; i < 78; i++) a += sx[ln][i] * sW1[i*32 + j];
    g_hA[(nodeBase + ln)*32 + j] = a;
}

__global__ void k_scatter32(const int* __restrict__ ei){
    int idx = blockIdx.x*256 + threadIdx.x;
    int e = idx >> 5, f = idx & 31;
    atomicAdd(&g_agg[ei[N_EDGES + e]*32 + f], g_hA[ei[e]*32 + f]);
}

__global__ __launch_bounds__(256) void k_gin1b(
    const void* b1, const void* W2, const void* b2,
    const void* bng, const void* bnb, const void* bnm, const void* bnv)
{
    const int F = g_isf32;
    __shared__ float sW2[32*32];
    __shared__ float sb1[32], sb2[32], sA[32], sB[32];
    __shared__ float st[8][32];
    int tid = threadIdx.x;
    for (int i = tid; i < 1024; i += 256) sW2[i] = LD(W2, i, F);
    if (tid < 32){
        sb1[tid] = LD(b1, tid, F); sb2[tid] = LD(b2, tid, F);
        float inv = LD(bng, tid, F) * rsqrtf(LD(bnv, tid, F) + BN_EPS);
        sA[tid] = inv;
        sB[tid] = LD(bnb, tid, F) - LD(bnm, tid, F) * inv;
    }
    __syncthreads();
    int ln = tid >> 5, j = tid & 31;
    int n = blockIdx.x*8 + ln;
    st[ln][j] = fmaxf(g_hA[n*32 + j] + g_agg[n*32 + j] + sb1[j], 0.f);
    __syncthreads();
    float t2 = sb2[j];
    #pragma unroll
    for (int i = 0; i < 32; i++) t2 += st[ln][i] * sW2[i*32 + j];
    t2 = fmaxf(t2, 0.f);
    g_hA[n*32 + j] = t2 * sA[j] + sB[j];
}

__global__ __launch_bounds__(256) void k_gin32L(
    const void* W1, const void* b1, const void* W2, const void* b2,
    const void* bng, const void* bnb, const void* bnm, const void* bnv, int l)
{
    const int F = g_isf32;
    const int oW = l*1024, ob = l*32, obn = (l+1)*32;
    __shared__ float sW1[32*32], sW2[32*32];
    __shared__ float sb1[32], sb2[32], sA[32], sB[32];
    __shared__ float sh[8][32], st[8][32];
    int tid = threadIdx.x;
    for (int i = tid; i < 1024; i += 256){ sW1[i] = LD(W1, oW + i, F); sW2[i] = LD(W2, oW + i, F); }
    if (tid < 32){
        sb1[tid] = LD(b1, ob + tid, F); sb2[tid] = LD(b2, ob + tid, F);
        float inv = LD(bng, obn + tid, F) * rsqrtf(LD(bnv, obn + tid, F) + BN_EPS);
        sA[tid] = inv;
        sB[tid] = LD(bnb, obn + tid, F) - LD(bnm, obn + tid, F) * inv;
    }
    int ln = tid >> 5, j = tid & 31;
    int n = blockIdx.x*8 + ln;
    sh[ln][j] = g_hA[n*32 + j] + g_agg[n*32 + j];
    __syncthreads();
    float t1 = sb1[j];
    #pragma unroll
    for (int i = 0; i < 32; i++) t1 += sh[ln][i] * sW1[i*32 + j];
    st[ln][j] = fmaxf(t1, 0.f);
    __syncthreads();
    float t2 = sb2[j];
    #pragma unroll
    for (int i = 0; i < 32; i++) t2 += st[ln][i] * sW2[i*32 + j];
    t2 = fmaxf(t2, 0.f);
    g_hA[n*32 + j] = t2 * sA[j] + sB[j];
}

__global__ void k_pool(const int* __restrict__ batch){
    int idx = blockIdx.x*256 + threadIdx.x;
    int n = idx >> 5;
    atomicAdd(&g_pooled[batch[n]*32 + (idx & 31)], g_hA[idx]);
}

__global__ void k_xd(const void* W, const void* bias){
    const int F = g_isf32;
    __shared__ float sp[32];
    int b = blockIdx.x, j = threadIdx.x;
    if (j < 32) sp[j] = g_pooled[b*32 + j];
    __syncthreads();
    float a = LD(bias, j, F);
    #pragma unroll
    for (int i = 0; i < 32; i++) a += sp[i] * LD(W, i*128 + j, F);
    g_xd[b*128 + j] = fmaxf(a, 0.f);
}

// ---------------- conv1 via 26-row embedding table ----------------

__global__ void k_P(const void* embed, const void* c1W){
    const int F = g_isf32;
    int idx = blockIdx.x*256 + threadIdx.x;
    if (idx >= 16*26*32) return;
    int o = idx & 31;
    int t = (idx >> 5) % 26;
    int k = idx / (32*26);
    float a = 0.f;
    for (int c = 0; c < 128; c++)
        a += LD(embed, t*128 + c, F) * LD(c1W, o*4096 + c*16 + k, F);
    g_P[(k*26 + t)*32 + o] = a;
}

__global__ void k_wsum(const void* c1W){
    const int F = g_isf32;
    int idx = blockIdx.x*256 + threadIdx.x;
    int o = idx >> 7, c = idx & 127;
    float a = 0.f;
    #pragma unroll
    for (int k = 0; k < 16; k++) a += LD(c1W, o*4096 + (128 + c)*16 + k, F);
    g_wsum[o*128 + c] = a;
}

__global__ void k_xdbias(const void* c1b){
    const int F = g_isf32;
    int idx = blockIdx.x*256 + threadIdx.x;
    int b = idx >> 5, o = idx & 31;
    float a = LD(c1b, o, F);
    for (int c = 0; c < 128; c++) a += g_xd[b*128 + c] * g_wsum[o*128 + c];
    g_xdb[idx] = a;
}

// writes [b][o][w] layout (stride C1S). o = tid&31 -> table-gather bank = lane
// (conflict-free); with o = tid>>3 the gathers were 8-way conflicted.
__global__ __launch_bounds__(256) void k_conv1L(
    const int* __restrict__ target,
    const void* g, const void* be, const void* m, const void* v, int obn)
{
    const int F = g_isf32;
    __shared__ float sP[16*26*32];
    __shared__ int   stg[LSEQ];
    __shared__ float sxb[32], sA[32], sB[32];
    int b = blockIdx.x, tid = threadIdx.x;
    for (int i = tid; i < 16*26*32; i += 256) sP[i] = g_P[i];
    for (int i = tid; i < LSEQ; i += 256) stg[i] = target[b*LSEQ + i];
    if (tid < 32){
        sxb[tid] = g_xdb[b*32 + tid];
        float inv = LD(g, obn + tid, F) * rsqrtf(LD(v, obn + tid, F) + BN_EPS);
        sA[tid] = inv;
        sB[tid] = LD(be, obn + tid, F) - LD(m, obn + tid, F) * inv;
    }
    __syncthreads();
    int o = tid & 31, wsub = tid >> 5;
    float xb = sxb[o], aa = sA[o], bb = sB[o];
    for (int w = wsub; w < W1O; w += 8){
        float a = xb;
        #pragma unroll
        for (int k = 0; k < 16; k++)
            a += sP[(k*26 + stg[w + k])*32 + o];
        g_c1o[(b*32 + o)*C1S + w] = fmaxf(a * aa + bb, 0.f);
    }
}

// ---------------- conv2/conv3 via MFMA, double-bf16 split (f32-accurate) ------
// Per tap kt: C[w][o] += In[w+kt][c]*W[c][o]; each f32 split hi/lo bf16,
// C += Ah*Bh + Ah*Bl + Al*Bh (3 MFMAs, Al*Bl ~2^-18 dropped).
// Tile: 128 w x 32 o per block; 4 waves = 2 w-halves x 2 o-halves,
// each wave 64 w x 16 o = 4 m-tiles x 1 n-frag. Taps in 4 passes of 4
// (43.8 KB LDS -> 3 blocks/CU; weight stores c-fastest -> conflict-free).
// A-frag: A[m=lane&15][k=quad*8+j] = sA*[w0+m+kt][quad*8+j]   (ds_read_b128)
// B-frag: B[k=quad*8+j][n=lane&15] = sB*[kt][o][quad*8+j]
// C/D   : col(o)=lane&15, row(w)=quad*4+reg                    (m89/m91)

#define CT_W 128
#define CT_R 144     // 128 + 15 halo, padded
#define CPAD 40      // c-row pad: 80 B = 16B-aligned rows, 2-way bank alias (free)

__global__ __launch_bounds__(256) void k_cmfma(
    int sel, int Wvalid, int Wout, int inStride,
    const void* Wt, const void* bias, const void* g, const void* be,
    const void* m, const void* v, int obn)
{
    const int F = g_isf32;
    const float* in = (sel == 0) ? g_c1o : g_c2o;
    __shared__ __attribute__((aligned(16))) unsigned short sAh[CT_R*CPAD]; // 11520 B
    __shared__ __attribute__((aligned(16))) unsigned short sAl[CT_R*CPAD]; // 11520 B
    __shared__ __attribute__((aligned(16))) unsigned short sBh[4*32*CPAD]; // 10240 B
    __shared__ __attribute__((aligned(16))) unsigned short sBl[4*32*CPAD]; // 10240 B
    __shared__ float sSc[32], sOf[32];
    int tid = threadIdx.x;
    int b = blockIdx.x >> 3;
    int tile = blockIdx.x & 7;
    int wbase = tile * CT_W;

    // stage input tile (hi/lo split); coalesced along w per channel row
    for (int c = 0; c < 32; c++){
        const float* src = in + (b*32 + c)*inStride;
        if (tid < CT_R){
            int wg_ = wbase + tid;
            float xv = (wg_ < Wvalid) ? src[wg_] : 0.f;
            unsigned short h = f2b(xv);
            sAh[tid*CPAD + c] = h;
            sAl[tid*CPAD + c] = f2b(xv - bb2f(h));
        }
    }
    if (tid < 32){
        float inv = LD(g, obn + tid, F) * rsqrtf(LD(v, obn + tid, F) + BN_EPS);
        sSc[tid] = inv;
        sOf[tid] = LD(be, obn + tid, F) + (LD(bias, tid, F) - LD(m, obn + tid, F)) * inv;
    }

    int lane = tid & 63;
    int wv = tid >> 6;
    int ml = lane & 15, quad = lane >> 4;
    int wgrp = wv & 1;           // w-half: 0 -> w 0..63, 1 -> 64..127
    int ogrp = wv >> 1;          // o-half: o = ml + ogrp*16

    f4v acc[4];
    #pragma unroll
    for (int mt = 0; mt < 4; mt++) acc[mt] = (f4v){0.f, 0.f, 0.f, 0.f};

    for (int kp = 0; kp < 4; kp++){
        __syncthreads();         // sA visible (kp=0) / previous-pass B reads done
        // stage 4-tap weight block hi/lo; c fastest -> consecutive lanes write
        // consecutive u16 (2 lanes/dword-bank = free, was 16-way conflicted)
        for (int i = tid; i < 4096; i += 256){
            int c = i & 31, o = (i >> 5) & 31, kt4 = i >> 10;
            float wv_ = LD(Wt, o*512 + c*16 + kp*4 + kt4, F);
            unsigned short h = f2b(wv_);
            sBh[(kt4*32 + o)*CPAD + c] = h;
            sBl[(kt4*32 + o)*CPAD + c] = f2b(wv_ - bb2f(h));
        }
        __syncthreads();
        for (int kt = 0; kt < 4; kt++){
            int ktg = kp*4 + kt;
            const int bidx = (kt*32 + ogrp*16 + ml)*CPAD + quad*8;
            s8v bh = *(const s8v*)&sBh[bidx];
            s8v bl = *(const s8v*)&sBl[bidx];
            #pragma unroll
            for (int mt = 0; mt < 4; mt++){
                int row = wgrp*64 + mt*16 + ml + ktg;
                const int aidx = row*CPAD + quad*8;
                s8v ah = *(const s8v*)&sAh[aidx];
                s8v al = *(const s8v*)&sAl[aidx];
                acc[mt] = __builtin_amdgcn_mfma_f32_16x16x32_bf16(ah, bh, acc[mt], 0, 0, 0);
                acc[mt] = __builtin_amdgcn_mfma_f32_16x16x32_bf16(ah, bl, acc[mt], 0, 0, 0);
                acc[mt] = __builtin_amdgcn_mfma_f32_16x16x32_bf16(al, bh, acc[mt], 0, 0, 0);
            }
        }
    }

    int o = ogrp*16 + ml;
    float sc = sSc[o], of = sOf[o];
    #pragma unroll
    for (int mt = 0; mt < 4; mt++){
        int w0 = wbase + wgrp*64 + mt*16 + quad*4;
        f4v a = acc[mt];
        float y0 = fmaxf(a.x*sc + of, 0.f);
        float y1 = fmaxf(a.y*sc + of, 0.f);
        float y2 = fmaxf(a.z*sc + of, 0.f);
        float y3 = fmaxf(a.w*sc + of, 0.f);
        if (sel == 0){
            float* dst = &g_c2o[(b*32 + o)*C2S + w0];
            if (w0 + 3 < Wout){
                *(float4*)dst = make_float4(y0, y1, y2, y3);
            } else if (w0 < Wout){
                dst[0] = y0;
                if (w0+1 < Wout) dst[1] = y1;
                if (w0+2 < Wout) dst[2] = y2;
                if (w0+3 < Wout) dst[3] = y3;
            }
        } else {
            if (w0 < Wout){
                float mx = y0;
                if (w0+1 < Wout) mx = fmaxf(mx, y1);
                if (w0+2 < Wout) mx = fmaxf(mx, y2);
                if (w0+3 < Wout) mx = fmaxf(mx, y3);
                atomicMax((int*)&g_xcm[b*32 + o], __float_as_int(mx));
            }
        }
    }
}

// ---------------- FC tail ----------------

__global__ void k_xcf(const void* W, const void* bias,
                      const void* g, const void* be, const void* m, const void* v){
    const int F = g_isf32;
    __shared__ float sp[32];
    int b = blockIdx.x, j = threadIdx.x;
    if (j < 32) sp[j] = g_xcm[b*32 + j];
    __syncthreads();
    float a = LD(bias, j, F);
    #pragma unroll
    for (int i = 0; i < 32; i++) a += sp[i] * LD(W, i*128 + j, F);
    float inv = LD(g, j, F) * rsqrtf(LD(v, j, F) + BN_EPS);
    a = (a - LD(m, j, F)) * inv + LD(be, j, F);
    g_xcf[b*128 + j] = fmaxf(a, 0.f);
}

__global__ __launch_bounds__(256) void k_fc1(const void* W, const void* bias){
    const int F = g_isf32;
    __shared__ float sz[256];
    int b = blockIdx.x >> 2;
    int j = ((blockIdx.x & 3) << 8) + threadIdx.x;
    int t = threadIdx.x;
    sz[t] = (t < 128) ? g_xd[b*128 + t] : g_xcf[b*128 + (t - 128)];
    __syncthreads();
    float a = LD(bias, j, F);
    for (int i = 0; i < 256; i++) a += sz[i] * LD(W, i*1024 + j, F);
    g_z1[b*1024 + j] = fmaxf(a, 0.f);
}

__global__ __launch_bounds__(256) void k_fc2(const void* W, const void* bias){
    const int F = g_isf32;
    __shared__ float sz[1024];
    int b = blockIdx.x, t = threadIdx.x;
    for (int i = t; i < 1024; i += 256) sz[i] = g_z1[b*1024 + i];
    __syncthreads();
    float a = LD(bias, t, F);
    for (int i = 0; i < 1024; i++) a += sz[i] * LD(W, i*256 + t, F);
    g_z2[b*256 + t] = fmaxf(a, 0.f);
}

__global__ void k_out(const void* W, const void* bias, void* out){
    const int F = g_isf32;
    __shared__ float red[256];
    int b = blockIdx.x, t = threadIdx.x;
    red[t] = g_z2[b*256 + t] * LD(W, t, F);
    __syncthreads();
    for (int s = 128; s > 0; s >>= 1){
        if (t < s) red[t] += red[t + s];
        __syncthreads();
    }
    if (t == 0){
        float r = red[0] + LD(bias, 0, F);
        if (F) ((float*)out)[b] = r;
        else   ((bf16*)out)[b] = __float2bfloat16(r);
    }
}

// ---------------- launch ----------------

extern "C" void kernel_launch(void* const* d_in, const int* in_sizes, int n_in,
                              void* d_out, int out_size, void* d_ws, size_t ws_size,
                              hipStream_t stream)
{
    (void)in_sizes; (void)n_in; (void)out_size; (void)d_ws; (void)ws_size;
    const void* x      = d_in[0];
    const int*  ei     = (const int*)d_in[1];
    const int*  batch  = (const int*)d_in[2];
    const int*  target = (const int*)d_in[3];
    const void* g1W1 = d_in[4];  const void* g1b1 = d_in[5];
    const void* g1W2 = d_in[6];  const void* g1b2 = d_in[7];
    const void* gW1  = d_in[8];  const void* gb1  = d_in[9];
    const void* gW2  = d_in[10]; const void* gb2  = d_in[11];
    const void* bng  = d_in[12]; const void* bnb  = d_in[13];
    const void* bnm  = d_in[14]; const void* bnv  = d_in[15];
    const void* fcxdW = d_in[16]; const void* fcxdb = d_in[17];
    const void* embed = d_in[18];
    const void* c1W = d_in[19]; const void* c1b = d_in[20];
    const void* c2W = d_in[21]; const void* c2b = d_in[22];
    const void* c3W = d_in[23]; const void* c3b = d_in[24];
    const void* cbng = d_in[25]; const void* cbnb = d_in[26];
    const void* cbnm = d_in[27]; const void* cbnv = d_in[28];
    const void* fcxcW = d_in[29]; const void* fcxcb = d_in[30];
    const void* bnfcg = d_in[31]; const void* bnfcb = d_in[32];
    const void* bnfcm = d_in[33]; const void* bnfcv = d_in[34];
    const void* fc1W = d_in[35]; const void* fc1b = d_in[36];
    const void* fc2W = d_in[37]; const void* fc2b = d_in[38];
    const void* outW = d_in[39]; const void* outb = d_in[40];

    k_dtype<<<1, 64, 0, stream>>>(x);

    // ---- GIN layer 1 (projected scatter) ----
    k_proj78<<<N_NODES/8, 256, 0, stream>>>(x, g1W1);
    k_zero_agg<<<N_NODES*32/256, 256, 0, stream>>>();
    k_zero_misc<<<NB*32/256, 256, 0, stream>>>();
    k_scatter32<<<(N_EDGES*32)/256, 256, 0, stream>>>(ei);
    k_gin1b<<<N_NODES/8, 256, 0, stream>>>(g1b1, g1W2, g1b2, bng, bnb, bnm, bnv);
    // ---- GIN layers 2..5 ----
    for (int l = 0; l < 4; l++){
        k_zero_agg<<<N_NODES*32/256, 256, 0, stream>>>();
        k_scatter32<<<(N_EDGES*32)/256, 256, 0, stream>>>(ei);
        k_gin32L<<<N_NODES/8, 256, 0, stream>>>(gW1, gb1, gW2, gb2,
                                                bng, bnb, bnm, bnv, l);
    }
    // ---- pool + xd ----
    k_pool<<<(N_NODES*32)/256, 256, 0, stream>>>(batch);
    k_xd<<<NB, 128, 0, stream>>>(fcxdW, fcxdb);
    // ---- conv1 prep ----
    k_P<<<(16*26*32 + 255)/256, 256, 0, stream>>>(embed, c1W);
    k_wsum<<<16, 256, 0, stream>>>(c1W);
    k_xdbias<<<32, 256, 0, stream>>>(c1b);
    // ---- conv chain ----
    k_conv1L<<<NB, 256, 0, stream>>>(target, cbng, cbnb, cbnm, cbnv, 0);
    k_cmfma<<<NB*8, 256, 0, stream>>>(0, W1O, W2O, C1S, c2W,
                                      c2b, cbng, cbnb, cbnm, cbnv, 32);
    k_cmfma<<<NB*8, 256, 0, stream>>>(1, W2O, W3O, C2S, c3W,
                                      c3b, cbng, cbnb, cbnm, cbnv, 64);
    // ---- FC tail ----
    k_xcf<<<NB, 128, 0, stream>>>(fcxcW, fcxcb, bnfcg, bnfcb, bnfcm, bnfcv);
    k_fc1<<<NB*4, 256, 0, stream>>>(fc1W, fc1b);
    k_fc2<<<NB, 256, 0, stream>>>(fc2W, fc2b);
    k_out<<<NB, 256, 0, stream>>>(outW, outb, d_out);
}

// Round 10
// 660.355 us; speedup vs baseline: 3.3002x; 1.1150x over previous
//
#include <hip/hip_runtime.h>
#include <hip/hip_bf16.h>

typedef __hip_bfloat16 bf16;
__device__ __forceinline__ float b2f(bf16 v){ return __bfloat162float(v); }

typedef __attribute__((ext_vector_type(8))) short s8v;
typedef __attribute__((ext_vector_type(4))) float f4v;

#define N_NODES 16384
#define N_EDGES 65536
#define NB 256
#define LSEQ 1000
#define BN_EPS 1e-5f
#define W1O 985
#define W2O 970
#define W3O 955
#define C1S 988          // g_c1o row stride (floats), layout [b][32 ch][C1S]
#define C2S 976          // g_c2o row stride (floats), layout [b][32 ch][C2S]

// ---- dtype flag: 1 if float inputs are f32, 0 if bf16 (measured: f32 on this harness) ----
__device__ int g_isf32;

__device__ __forceinline__ float LD(const void* p, int i, int f){
    return f ? ((const float*)p)[i] : b2f(((const bf16*)p)[i]);
}

// f32 -> bf16 bits, round-to-nearest-even
__device__ __forceinline__ unsigned short f2b(float x){
    unsigned u = __float_as_uint(x);
    return (unsigned short)((u + 0x7FFFu + ((u >> 16) & 1u)) >> 16);
}
__device__ __forceinline__ float bb2f(unsigned short h){
    return __uint_as_float(((unsigned)h) << 16);
}

__global__ void k_dtype(const void* x){
    if (threadIdx.x != 0 || blockIdx.x != 0) return;
    const unsigned short* u = (const unsigned short*)x;
    int insane = 0;
    for (int i = 0; i < 512; i++){
        unsigned short h = u[i];
        int ex = (h >> 7) & 0xFF;
        if (!(h == 0 || (ex >= 96 && ex <= 142))) insane++;
    }
    g_isf32 = (insane > 50) ? 1 : 0;
}

// ---- intermediates in device globals ----
__device__ float g_hA[N_NODES*32];
__device__ float g_agg[N_NODES*32];
__device__ float g_pooled[NB*32];
__device__ float g_xd[NB*128];
__device__ float g_P[16*26*32];
__device__ float g_wsum[32*128];
__device__ float g_xdb[NB*32];
__device__ float g_xcm[NB*32];
__device__ float g_xcf[NB*128];
__device__ float g_z1[NB*1024];
__device__ float g_z2[NB*256];
__device__ float g_c1o[NB*32*C1S];   // 32.4 MB, [b][o][w]
__device__ float g_c2o[NB*32*C2S];   // 32.0 MB, [b][o][w]
// pre-packed conv weights, hi/lo bf16, in staging-linear order:
// index = kp*4096 + kt4*1024 + o*32 + c   (kt = kp*4 + kt4)
__device__ unsigned short g_wph[2][16384];
__device__ unsigned short g_wpl[2][16384];

__global__ void k_zero_agg(){ g_agg[blockIdx.x*256 + threadIdx.x] = 0.f; }
__global__ void k_zero_misc(){
    int i = blockIdx.x*256 + threadIdx.x;
    g_pooled[i] = 0.f;
    g_xcm[i] = 0.f;
}

// ---- weight pre-pack: scattered reads once, coalesced writes ----
__global__ void k_wpack(const void* w2, const void* w3){
    const int F = g_isf32;
    int idx = blockIdx.x*256 + threadIdx.x;      // 32768 threads
    int sel = idx >> 14;
    int r = idx & 16383;
    int kp = r >> 12, kt4 = (r >> 10) & 3;
    int o = (r >> 5) & 31, c = r & 31;
    int kt = kp*4 + kt4;
    const void* Wt = sel ? w3 : w2;
    float wv = LD(Wt, o*512 + c*16 + kt, F);
    unsigned short h = f2b(wv);
    g_wph[sel][r] = h;
    g_wpl[sel][r] = f2b(wv - bb2f(h));
}

// ---------------- GIN branch ----------------

__global__ __launch_bounds__(256) void k_proj78(const void* x, const void* W1)
{
    const int F = g_isf32;
    __shared__ float sW1[78*32];
    __shared__ float sx[8][78];
    int tid = threadIdx.x;
    for (int i = tid; i < 78*32; i += 256) sW1[i] = LD(W1, i, F);
    int nodeBase = blockIdx.x * 8;
    for (int i = tid; i < 8*78; i += 256){
        int ln = i / 78, f = i - ln*78;
        sx[ln][f] = LD(x, (nodeBase + ln)*78 + f, F);
    }
    __syncthreads();
    int ln = tid >> 5, j = tid & 31;
    float a = 0.f;
    #pragma unroll 6
    for (int i = 0; i < 78; i++) a += sx[ln][i] * sW1[i*32 + j];
    g_hA[(nodeBase + ln)*32 + j] = a;
}

__global__ void k_scatter32(const int* __restrict__ ei){
    int idx = blockIdx.x*256 + threadIdx.x;
    int e = idx >> 5, f = idx & 31;
    atomicAdd(&g_agg[ei[N_EDGES + e]*32 + f], g_hA[ei[e]*32 + f]);
}

// also zeroes g_agg for the next layer's scatter (same thread, same location)
__global__ __launch_bounds__(256) void k_gin1b(
    const void* b1, const void* W2, const void* b2,
    const void* bng, const void* bnb, const void* bnm, const void* bnv)
{
    const int F = g_isf32;
    __shared__ float sW2[32*32];
    __shared__ float sb1[32], sb2[32], sA[32], sB[32];
    __shared__ float st[8][32];
    int tid = threadIdx.x;
    for (int i = tid; i < 1024; i += 256) sW2[i] = LD(W2, i, F);
    if (tid < 32){
        sb1[tid] = LD(b1, tid, F); sb2[tid] = LD(b2, tid, F);
        float inv = LD(bng, tid, F) * rsqrtf(LD(bnv, tid, F) + BN_EPS);
        sA[tid] = inv;
        sB[tid] = LD(bnb, tid, F) - LD(bnm, tid, F) * inv;
    }
    __syncthreads();
    int ln = tid >> 5, j = tid & 31;
    int n = blockIdx.x*8 + ln;
    st[ln][j] = fmaxf(g_hA[n*32 + j] + g_agg[n*32 + j] + sb1[j], 0.f);
    g_agg[n*32 + j] = 0.f;
    __syncthreads();
    float t2 = sb2[j];
    #pragma unroll
    for (int i = 0; i < 32; i++) t2 += st[ln][i] * sW2[i*32 + j];
    t2 = fmaxf(t2, 0.f);
    g_hA[n*32 + j] = t2 * sA[j] + sB[j];
}

__global__ __launch_bounds__(256) void k_gin32L(
    const void* W1, const void* b1, const void* W2, const void* b2,
    const void* bng, const void* bnb, const void* bnm, const void* bnv, int l)
{
    const int F = g_isf32;
    const int oW = l*1024, ob = l*32, obn = (l+1)*32;
    __shared__ float sW1[32*32], sW2[32*32];
    __shared__ float sb1[32], sb2[32], sA[32], sB[32];
    __shared__ float sh[8][32], st[8][32];
    int tid = threadIdx.x;
    for (int i = tid; i < 1024; i += 256){ sW1[i] = LD(W1, oW + i, F); sW2[i] = LD(W2, oW + i, F); }
    if (tid < 32){
        sb1[tid] = LD(b1, ob + tid, F); sb2[tid] = LD(b2, ob + tid, F);
        float inv = LD(bng, obn + tid, F) * rsqrtf(LD(bnv, obn + tid, F) + BN_EPS);
        sA[tid] = inv;
        sB[tid] = LD(bnb, obn + tid, F) - LD(bnm, obn + tid, F) * inv;
    }
    int ln = tid >> 5, j = tid & 31;
    int n = blockIdx.x*8 + ln;
    sh[ln][j] = g_hA[n*32 + j] + g_agg[n*32 + j];
    g_agg[n*32 + j] = 0.f;
    __syncthreads();
    float t1 = sb1[j];
    #pragma unroll
    for (int i = 0; i < 32; i++) t1 += sh[ln][i] * sW1[i*32 + j];
    st[ln][j] = fmaxf(t1, 0.f);
    __syncthreads();
    float t2 = sb2[j];
    #pragma unroll
    for (int i = 0; i < 32; i++) t2 += st[ln][i] * sW2[i*32 + j];
    t2 = fmaxf(t2, 0.f);
    g_hA[n*32 + j] = t2 * sA[j] + sB[j];
}

__global__ void k_pool(const int* __restrict__ batch){
    int idx = blockIdx.x*256 + threadIdx.x;
    int n = idx >> 5;
    atomicAdd(&g_pooled[batch[n]*32 + (idx & 31)], g_hA[idx]);
}

__global__ void k_xd(const void* W, const void* bias){
    const int F = g_isf32;
    __shared__ float sp[32];
    int b = blockIdx.x, j = threadIdx.x;
    if (j < 32) sp[j] = g_pooled[b*32 + j];
    __syncthreads();
    float a = LD(bias, j, F);
    #pragma unroll
    for (int i = 0; i < 32; i++) a += sp[i] * LD(W, i*128 + j, F);
    g_xd[b*128 + j] = fmaxf(a, 0.f);
}

// ---------------- conv1 via 26-row embedding table ----------------

__global__ void k_P(const void* embed, const void* c1W){
    const int F = g_isf32;
    int idx = blockIdx.x*256 + threadIdx.x;
    if (idx >= 16*26*32) return;
    int o = idx & 31;
    int t = (idx >> 5) % 26;
    int k = idx / (32*26);
    float a = 0.f;
    for (int c = 0; c < 128; c++)
        a += LD(embed, t*128 + c, F) * LD(c1W, o*4096 + c*16 + k, F);
    g_P[(k*26 + t)*32 + o] = a;
}

__global__ void k_wsum(const void* c1W){
    const int F = g_isf32;
    int idx = blockIdx.x*256 + threadIdx.x;
    int o = idx >> 7, c = idx & 127;
    float a = 0.f;
    #pragma unroll
    for (int k = 0; k < 16; k++) a += LD(c1W, o*4096 + (128 + c)*16 + k, F);
    g_wsum[o*128 + c] = a;
}

__global__ void k_xdbias(const void* c1b){
    const int F = g_isf32;
    int idx = blockIdx.x*256 + threadIdx.x;
    int b = idx >> 5, o = idx & 31;
    float a = LD(c1b, o, F);
    for (int c = 0; c < 128; c++) a += g_xd[b*128 + c] * g_wsum[o*128 + c];
    g_xdb[idx] = a;
}

// writes [b][o][w] layout (stride C1S). o = tid&31 -> table-gather bank = lane
__global__ __launch_bounds__(256) void k_conv1L(
    const int* __restrict__ target,
    const void* g, const void* be, const void* m, const void* v, int obn)
{
    const int F = g_isf32;
    __shared__ float sP[16*26*32];
    __shared__ int   stg[LSEQ];
    __shared__ float sxb[32], sA[32], sB[32];
    int b = blockIdx.x, tid = threadIdx.x;
    for (int i = tid; i < 16*26*32; i += 256) sP[i] = g_P[i];
    for (int i = tid; i < LSEQ; i += 256) stg[i] = target[b*LSEQ + i];
    if (tid < 32){
        sxb[tid] = g_xdb[b*32 + tid];
        float inv = LD(g, obn + tid, F) * rsqrtf(LD(v, obn + tid, F) + BN_EPS);
        sA[tid] = inv;
        sB[tid] = LD(be, obn + tid, F) - LD(m, obn + tid, F) * inv;
    }
    __syncthreads();
    int o = tid & 31, wsub = tid >> 5;
    float xb = sxb[o], aa = sA[o], bb = sB[o];
    for (int w = wsub; w < W1O; w += 8){
        float a = xb;
        #pragma unroll
        for (int k = 0; k < 16; k++)
            a += sP[(k*26 + stg[w + k])*32 + o];
        g_c1o[(b*32 + o)*C1S + w] = fmaxf(a * aa + bb, 0.f);
    }
}

// ---------------- conv2/conv3 via MFMA, double-bf16 split (f32-accurate) ------
// Identical compute structure to the r9 passing kernel; only the weight
// staging source changed: pre-packed hi/lo bf16 read LINEARLY (coalesced,
// 128 B/wave-instr) instead of 64-B-strided scattered f32 loads.

#define CT_W 128
#define CT_R 144     // 128 + 15 halo, padded
#define CPAD 40      // c-row pad: 80 B = 16B-aligned rows, 2-way bank alias (free)

__global__ __launch_bounds__(256) void k_cmfma(
    int sel, int Wvalid, int Wout, int inStride,
    const void* bias, const void* g, const void* be,
    const void* m, const void* v, int obn)
{
    const int F = g_isf32;
    const float* in = (sel == 0) ? g_c1o : g_c2o;
    __shared__ __attribute__((aligned(16))) unsigned short sAh[CT_R*CPAD]; // 11520 B
    __shared__ __attribute__((aligned(16))) unsigned short sAl[CT_R*CPAD]; // 11520 B
    __shared__ __attribute__((aligned(16))) unsigned short sBh[4*32*CPAD]; // 10240 B
    __shared__ __attribute__((aligned(16))) unsigned short sBl[4*32*CPAD]; // 10240 B
    __shared__ float sSc[32], sOf[32];
    int tid = threadIdx.x;
    int b = blockIdx.x >> 3;
    int tile = blockIdx.x & 7;
    int wbase = tile * CT_W;

    // stage input tile (hi/lo split); coalesced along w per channel row
    for (int c = 0; c < 32; c++){
        const float* src = in + (b*32 + c)*inStride;
        if (tid < CT_R){
            int wg_ = wbase + tid;
            float xv = (wg_ < Wvalid) ? src[wg_] : 0.f;
            unsigned short h = f2b(xv);
            sAh[tid*CPAD + c] = h;
            sAl[tid*CPAD + c] = f2b(xv - bb2f(h));
        }
    }
    if (tid < 32){
        float inv = LD(g, obn + tid, F) * rsqrtf(LD(v, obn + tid, F) + BN_EPS);
        sSc[tid] = inv;
        sOf[tid] = LD(be, obn + tid, F) + (LD(bias, tid, F) - LD(m, obn + tid, F)) * inv;
    }

    int lane = tid & 63;
    int wv = tid >> 6;
    int ml = lane & 15, quad = lane >> 4;
    int wgrp = wv & 1;           // w-half: 0 -> w 0..63, 1 -> 64..127
    int ogrp = wv >> 1;          // o-half: o = ml + ogrp*16

    const unsigned short* wph = &g_wph[sel][0];
    const unsigned short* wpl = &g_wpl[sel][0];

    f4v acc[4];
    #pragma unroll
    for (int mt = 0; mt < 4; mt++) acc[mt] = (f4v){0.f, 0.f, 0.f, 0.f};

    for (int kp = 0; kp < 4; kp++){
        __syncthreads();         // sA visible (kp=0) / previous-pass B reads done
        // stage 4-tap weight block: LINEAR coalesced u16 reads, LDS writes
        // c-fastest (2 lanes/dword-bank = free)
        for (int i = tid; i < 4096; i += 256){
            int c = i & 31, o = (i >> 5) & 31, kt4 = i >> 10;
            int ldsi = (kt4*32 + o)*CPAD + c;
            sBh[ldsi] = wph[kp*4096 + i];
            sBl[ldsi] = wpl[kp*4096 + i];
        }
        __syncthreads();
        for (int kt = 0; kt < 4; kt++){
            int ktg = kp*4 + kt;
            const int bidx = (kt*32 + ogrp*16 + ml)*CPAD + quad*8;
            s8v bh = *(const s8v*)&sBh[bidx];
            s8v bl = *(const s8v*)&sBl[bidx];
            #pragma unroll
            for (int mt = 0; mt < 4; mt++){
                int row = wgrp*64 + mt*16 + ml + ktg;
                const int aidx = row*CPAD + quad*8;
                s8v ah = *(const s8v*)&sAh[aidx];
                s8v al = *(const s8v*)&sAl[aidx];
                acc[mt] = __builtin_amdgcn_mfma_f32_16x16x32_bf16(ah, bh, acc[mt], 0, 0, 0);
                acc[mt] = __builtin_amdgcn_mfma_f32_16x16x32_bf16(ah, bl, acc[mt], 0, 0, 0);
                acc[mt] = __builtin_amdgcn_mfma_f32_16x16x32_bf16(al, bh, acc[mt], 0, 0, 0);
            }
        }
    }

    int o = ogrp*16 + ml;
    float sc = sSc[o], of = sOf[o];
    #pragma unroll
    for (int mt = 0; mt < 4; mt++){
        int w0 = wbase + wgrp*64 + mt*16 + quad*4;
        f4v a = acc[mt];
        float y0 = fmaxf(a.x*sc + of, 0.f);
        float y1 = fmaxf(a.y*sc + of, 0.f);
        float y2 = fmaxf(a.z*sc + of, 0.f);
        float y3 = fmaxf(a.w*sc + of, 0.f);
        if (sel == 0){
            float* dst = &g_c2o[(b*32 + o)*C2S + w0];
            if (w0 + 3 < Wout){
                *(float4*)dst = make_float4(y0, y1, y2, y3);
            } else if (w0 < Wout){
                dst[0] = y0;
                if (w0+1 < Wout) dst[1] = y1;
                if (w0+2 < Wout) dst[2] = y2;
                if (w0+3 < Wout) dst[3] = y3;
            }
        } else {
            if (w0 < Wout){
                float mx = y0;
                if (w0+1 < Wout) mx = fmaxf(mx, y1);
                if (w0+2 < Wout) mx = fmaxf(mx, y2);
                if (w0+3 < Wout) mx = fmaxf(mx, y3);
                atomicMax((int*)&g_xcm[b*32 + o], __float_as_int(mx));
            }
        }
    }
}

// ---------------- FC tail ----------------

__global__ void k_xcf(const void* W, const void* bias,
                      const void* g, const void* be, const void* m, const void* v){
    const int F = g_isf32;
    __shared__ float sp[32];
    int b = blockIdx.x, j = threadIdx.x;
    if (j < 32) sp[j] = g_xcm[b*32 + j];
    __syncthreads();
    float a = LD(bias, j, F);
    #pragma unroll
    for (int i = 0; i < 32; i++) a += sp[i] * LD(W, i*128 + j, F);
    float inv = LD(g, j, F) * rsqrtf(LD(v, j, F) + BN_EPS);
    a = (a - LD(m, j, F)) * inv + LD(be, j, F);
    g_xcf[b*128 + j] = fmaxf(a, 0.f);
}

__global__ __launch_bounds__(256) void k_fc1(const void* W, const void* bias){
    const int F = g_isf32;
    __shared__ float sz[256];
    int b = blockIdx.x >> 2;
    int j = ((blockIdx.x & 3) << 8) + threadIdx.x;
    int t = threadIdx.x;
    sz[t] = (t < 128) ? g_xd[b*128 + t] : g_xcf[b*128 + (t - 128)];
    __syncthreads();
    float a = LD(bias, j, F);
    for (int i = 0; i < 256; i++) a += sz[i] * LD(W, i*1024 + j, F);
    g_z1[b*1024 + j] = fmaxf(a, 0.f);
}

__global__ __launch_bounds__(256) void k_fc2(const void* W, const void* bias){
    const int F = g_isf32;
    __shared__ float sz[1024];
    int b = blockIdx.x, t = threadIdx.x;
    for (int i = t; i < 1024; i += 256) sz[i] = g_z1[b*1024 + i];
    __syncthreads();
    float a = LD(bias, t, F);
    for (int i = 0; i < 1024; i++) a += sz[i] * LD(W, i*256 + t, F);
    g_z2[b*256 + t] = fmaxf(a, 0.f);
}

__global__ void k_out(const void* W, const void* bias, void* out){
    const int F = g_isf32;
    __shared__ float red[256];
    int b = blockIdx.x, t = threadIdx.x;
    red[t] = g_z2[b*256 + t] * LD(W, t, F);
    __syncthreads();
    for (int s = 128; s > 0; s >>= 1){
        if (t < s) red[t] += red[t + s];
        __syncthreads();
    }
    if (t == 0){
        float r = red[0] + LD(bias, 0, F);
        if (F) ((float*)out)[b] = r;
        else   ((bf16*)out)[b] = __float2bfloat16(r);
    }
}

// ---------------- launch ----------------

extern "C" void kernel_launch(void* const* d_in, const int* in_sizes, int n_in,
                              void* d_out, int out_size, void* d_ws, size_t ws_size,
                              hipStream_t stream)
{
    (void)in_sizes; (void)n_in; (void)out_size; (void)d_ws; (void)ws_size;
    const void* x      = d_in[0];
    const int*  ei     = (const int*)d_in[1];
    const int*  batch  = (const int*)d_in[2];
    const int*  target = (const int*)d_in[3];
    const void* g1W1 = d_in[4];  const void* g1b1 = d_in[5];
    const void* g1W2 = d_in[6];  const void* g1b2 = d_in[7];
    const void* gW1  = d_in[8];  const void* gb1  = d_in[9];
    const void* gW2  = d_in[10]; const void* gb2  = d_in[11];
    const void* bng  = d_in[12]; const void* bnb  = d_in[13];
    const void* bnm  = d_in[14]; const void* bnv  = d_in[15];
    const void* fcxdW = d_in[16]; const void* fcxdb = d_in[17];
    const void* embed = d_in[18];
    const void* c1W = d_in[19]; const void* c1b = d_in[20];
    const void* c2W = d_in[21]; const void* c2b = d_in[22];
    const void* c3W = d_in[23]; const void* c3b = d_in[24];
    const void* cbng = d_in[25]; const void* cbnb = d_in[26];
    const void* cbnm = d_in[27]; const void* cbnv = d_in[28];
    const void* fcxcW = d_in[29]; const void* fcxcb = d_in[30];
    const void* bnfcg = d_in[31]; const void* bnfcb = d_in[32];
    const void* bnfcm = d_in[33]; const void* bnfcv = d_in[34];
    const void* fc1W = d_in[35]; const void* fc1b = d_in[36];
    const void* fc2W = d_in[37]; const void* fc2b = d_in[38];
    const void* outW = d_in[39]; const void* outb = d_in[40];

    k_dtype<<<1, 64, 0, stream>>>(x);
    k_wpack<<<128, 256, 0, stream>>>(c2W, c3W);

    // ---- GIN layer 1 (projected scatter) ----
    k_proj78<<<N_NODES/8, 256, 0, stream>>>(x, g1W1);
    k_zero_agg<<<N_NODES*32/256, 256, 0, stream>>>();
    k_zero_misc<<<NB*32/256, 256, 0, stream>>>();
    k_scatter32<<<(N_EDGES*32)/256, 256, 0, stream>>>(ei);
    k_gin1b<<<N_NODES/8, 256, 0, stream>>>(g1b1, g1W2, g1b2, bng, bnb, bnm, bnv);
    // ---- GIN layers 2..5 (agg re-zeroed inside the previous gin kernel) ----
    for (int l = 0; l < 4; l++){
        k_scatter32<<<(N_EDGES*32)/256, 256, 0, stream>>>(ei);
        k_gin32L<<<N_NODES/8, 256, 0, stream>>>(gW1, gb1, gW2, gb2,
                                                bng, bnb, bnm, bnv, l);
    }
    // ---- pool + xd ----
    k_pool<<<(N_NODES*32)/256, 256, 0, stream>>>(batch);
    k_xd<<<NB, 128, 0, stream>>>(fcxdW, fcxdb);
    // ---- conv1 prep ----
    k_P<<<(16*26*32 + 255)/256, 256, 0, stream>>>(embed, c1W);
    k_wsum<<<16, 256, 0, stream>>>(c1W);
    k_xdbias<<<32, 256, 0, stream>>>(c1b);
    // ---- conv chain ----
    k_conv1L<<<NB, 256, 0, stream>>>(target, cbng, cbnb, cbnm, cbnv, 0);
    k_cmfma<<<NB*8, 256, 0, stream>>>(0, W1O, W2O, C1S,
                                      c2b, cbng, cbnb, cbnm, cbnv, 32);
    k_cmfma<<<NB*8, 256, 0, stream>>>(1, W2O, W3O, C2S,
                                      c3b, cbng, cbnb, cbnm, cbnv, 64);
    // ---- FC tail ----
    k_xcf<<<NB, 128, 0, stream>>>(fcxcW, fcxcb, bnfcg, bnfcb, bnfcm, bnfcv);
    k_fc1<<<NB*4, 256, 0, stream>>>(fc1W, fc1b);
    k_fc2<<<NB, 256, 0, stream>>>(fc2W, fc2b);
    k_out<<<NB, 256, 0, stream>>>(outW, outb, d_out);
}

// Round 11
// 542.418 us; speedup vs baseline: 4.0178x; 1.2174x over previous
//
#include <hip/hip_runtime.h>
#include <hip/hip_bf16.h>

typedef __hip_bfloat16 bf16;
__device__ __forceinline__ float b2f(bf16 v){ return __bfloat162float(v); }

typedef __attribute__((ext_vector_type(8))) short s8v;
typedef __attribute__((ext_vector_type(4))) float f4v;

#define N_NODES 16384
#define N_EDGES 65536
#define NB 256
#define LSEQ 1000
#define BN_EPS 1e-5f
#define W1O 985
#define W2O 970
#define W3O 955
#define C1S 988          // g_c1o row stride (floats), layout [b][32 ch][C1S]
#define C2S 976          // g_c2o row stride (floats), layout [b][32 ch][C2S]

// ---- dtype flag: 1 if float inputs are f32, 0 if bf16 (measured: f32 on this harness) ----
__device__ int g_isf32;

__device__ __forceinline__ float LD(const void* p, int i, int f){
    return f ? ((const float*)p)[i] : b2f(((const bf16*)p)[i]);
}

// f32 -> bf16 bits, round-to-nearest-even
__device__ __forceinline__ unsigned short f2b(float x){
    unsigned u = __float_as_uint(x);
    return (unsigned short)((u + 0x7FFFu + ((u >> 16) & 1u)) >> 16);
}
__device__ __forceinline__ float bb2f(unsigned short h){
    return __uint_as_float(((unsigned)h) << 16);
}

__global__ void k_dtype(const void* x){
    if (threadIdx.x != 0 || blockIdx.x != 0) return;
    const unsigned short* u = (const unsigned short*)x;
    int insane = 0;
    for (int i = 0; i < 512; i++){
        unsigned short h = u[i];
        int ex = (h >> 7) & 0xFF;
        if (!(h == 0 || (ex >= 96 && ex <= 142))) insane++;
    }
    g_isf32 = (insane > 50) ? 1 : 0;
}

// ---- intermediates in device globals ----
__device__ float g_hA[N_NODES*32];
__device__ float g_agg[N_NODES*32];
__device__ float g_pooled[NB*32];
__device__ float g_xd[NB*128];
__device__ float g_P[16*26*32];
__device__ float g_wsum[32*128];
__device__ float g_xdb[NB*32];
__device__ float g_xcm[NB*32];
__device__ float g_xcf[NB*128];
__device__ float g_z1[NB*1024];
__device__ float g_z2[NB*256];
__device__ float g_c1o[NB*32*C1S];   // 32.4 MB, [b][o][w]
__device__ float g_c2o[NB*32*C2S];   // 32.0 MB, [b][o][w]
// pre-packed conv weights, hi/lo bf16, in staging-linear order:
// index = kp*2048 + kt2*1024 + o*32 + c   (kt = kp*2 + kt2)
__device__ unsigned short g_wph[2][16384];
__device__ unsigned short g_wpl[2][16384];

__global__ void k_zero_agg(){ g_agg[blockIdx.x*256 + threadIdx.x] = 0.f; }
__global__ void k_zero_misc(){
    int i = blockIdx.x*256 + threadIdx.x;
    g_pooled[i] = 0.f;
    g_xcm[i] = 0.f;
}

// ---- weight pre-pack: scattered reads once, coalesced writes ----
__global__ void k_wpack(const void* w2, const void* w3){
    const int F = g_isf32;
    int idx = blockIdx.x*256 + threadIdx.x;      // 32768 threads
    int sel = idx >> 14;
    int r = idx & 16383;
    int kp = r >> 11, kt2 = (r >> 10) & 1;
    int o = (r >> 5) & 31, c = r & 31;
    int kt = kp*2 + kt2;
    const void* Wt = sel ? w3 : w2;
    float wv = LD(Wt, o*512 + c*16 + kt, F);
    unsigned short h = f2b(wv);
    g_wph[sel][r] = h;
    g_wpl[sel][r] = f2b(wv - bb2f(h));
}

// ---------------- GIN branch ----------------

__global__ __launch_bounds__(256) void k_proj78(const void* x, const void* W1)
{
    const int F = g_isf32;
    __shared__ float sW1[78*32];
    __shared__ float sx[8][78];
    int tid = threadIdx.x;
    for (int i = tid; i < 78*32; i += 256) sW1[i] = LD(W1, i, F);
    int nodeBase = blockIdx.x * 8;
    for (int i = tid; i < 8*78; i += 256){
        int ln = i / 78, f = i - ln*78;
        sx[ln][f] = LD(x, (nodeBase + ln)*78 + f, F);
    }
    __syncthreads();
    int ln = tid >> 5, j = tid & 31;
    float a = 0.f;
    #pragma unroll 6
    for (int i = 0; i < 78; i++) a += sx[ln][i] * sW1[i*32 + j];
    g_hA[(nodeBase + ln)*32 + j] = a;
}

__global__ void k_scatter32(const int* __restrict__ ei){
    int idx = blockIdx.x*256 + threadIdx.x;
    int e = idx >> 5, f = idx & 31;
    atomicAdd(&g_agg[ei[N_EDGES + e]*32 + f], g_hA[ei[e]*32 + f]);
}

// also zeroes g_agg for the next layer's scatter (same thread, same location)
__global__ __launch_bounds__(256) void k_gin1b(
    const void* b1, const void* W2, const void* b2,
    const void* bng, const void* bnb, const void* bnm, const void* bnv)
{
    const int F = g_isf32;
    __shared__ float sW2[32*32];
    __shared__ float sb1[32], sb2[32], sA[32], sB[32];
    __shared__ float st[8][32];
    int tid = threadIdx.x;
    for (int i = tid; i < 1024; i += 256) sW2[i] = LD(W2, i, F);
    if (tid < 32){
        sb1[tid] = LD(b1, tid, F); sb2[tid] = LD(b2, tid, F);
        float inv = LD(bng, tid, F) * rsqrtf(LD(bnv, tid, F) + BN_EPS);
        sA[tid] = inv;
        sB[tid] = LD(bnb, tid, F) - LD(bnm, tid, F) * inv;
    }
    __syncthreads();
    int ln = tid >> 5, j = tid & 31;
    int n = blockIdx.x*8 + ln;
    st[ln][j] = fmaxf(g_hA[n*32 + j] + g_agg[n*32 + j] + sb1[j], 0.f);
    g_agg[n*32 + j] = 0.f;
    __syncthreads();
    float t2 = sb2[j];
    #pragma unroll
    for (int i = 0; i < 32; i++) t2 += st[ln][i] * sW2[i*32 + j];
    t2 = fmaxf(t2, 0.f);
    g_hA[n*32 + j] = t2 * sA[j] + sB[j];
}

__global__ __launch_bounds__(256) void k_gin32L(
    const void* W1, const void* b1, const void* W2, const void* b2,
    const void* bng, const void* bnb, const void* bnm, const void* bnv, int l)
{
    const int F = g_isf32;
    const int oW = l*1024, ob = l*32, obn = (l+1)*32;
    __shared__ float sW1[32*32], sW2[32*32];
    __shared__ float sb1[32], sb2[32], sA[32], sB[32];
    __shared__ float sh[8][32], st[8][32];
    int tid = threadIdx.x;
    for (int i = tid; i < 1024; i += 256){ sW1[i] = LD(W1, oW + i, F); sW2[i] = LD(W2, oW + i, F); }
    if (tid < 32){
        sb1[tid] = LD(b1, ob + tid, F); sb2[tid] = LD(b2, ob + tid, F);
        float inv = LD(bng, obn + tid, F) * rsqrtf(LD(bnv, obn + tid, F) + BN_EPS);
        sA[tid] = inv;
        sB[tid] = LD(bnb, obn + tid, F) - LD(bnm, obn + tid, F) * inv;
    }
    int ln = tid >> 5, j = tid & 31;
    int n = blockIdx.x*8 + ln;
    sh[ln][j] = g_hA[n*32 + j] + g_agg[n*32 + j];
    g_agg[n*32 + j] = 0.f;
    __syncthreads();
    float t1 = sb1[j];
    #pragma unroll
    for (int i = 0; i < 32; i++) t1 += sh[ln][i] * sW1[i*32 + j];
    st[ln][j] = fmaxf(t1, 0.f);
    __syncthreads();
    float t2 = sb2[j];
    #pragma unroll
    for (int i = 0; i < 32; i++) t2 += st[ln][i] * sW2[i*32 + j];
    t2 = fmaxf(t2, 0.f);
    g_hA[n*32 + j] = t2 * sA[j] + sB[j];
}

__global__ void k_pool(const int* __restrict__ batch){
    int idx = blockIdx.x*256 + threadIdx.x;
    int n = idx >> 5;
    atomicAdd(&g_pooled[batch[n]*32 + (idx & 31)], g_hA[idx]);
}

__global__ void k_xd(const void* W, const void* bias){
    const int F = g_isf32;
    __shared__ float sp[32];
    int b = blockIdx.x, j = threadIdx.x;
    if (j < 32) sp[j] = g_pooled[b*32 + j];
    __syncthreads();
    float a = LD(bias, j, F);
    #pragma unroll
    for (int i = 0; i < 32; i++) a += sp[i] * LD(W, i*128 + j, F);
    g_xd[b*128 + j] = fmaxf(a, 0.f);
}

// ---------------- conv1 via 26-row embedding table ----------------

__global__ void k_P(const void* embed, const void* c1W){
    const int F = g_isf32;
    int idx = blockIdx.x*256 + threadIdx.x;
    if (idx >= 16*26*32) return;
    int o = idx & 31;
    int t = (idx >> 5) % 26;
    int k = idx / (32*26);
    float a = 0.f;
    for (int c = 0; c < 128; c++)
        a += LD(embed, t*128 + c, F) * LD(c1W, o*4096 + c*16 + k, F);
    g_P[(k*26 + t)*32 + o] = a;
}

__global__ void k_wsum(const void* c1W){
    const int F = g_isf32;
    int idx = blockIdx.x*256 + threadIdx.x;
    int o = idx >> 7, c = idx & 127;
    float a = 0.f;
    #pragma unroll
    for (int k = 0; k < 16; k++) a += LD(c1W, o*4096 + (128 + c)*16 + k, F);
    g_wsum[o*128 + c] = a;
}

__global__ void k_xdbias(const void* c1b){
    const int F = g_isf32;
    int idx = blockIdx.x*256 + threadIdx.x;
    int b = idx >> 5, o = idx & 31;
    float a = LD(c1b, o, F);
    for (int c = 0; c < 128; c++) a += g_xd[b*128 + c] * g_wsum[o*128 + c];
    g_xdb[idx] = a;
}

// writes [b][o][w] layout (stride C1S). o = tid&31 -> table-gather bank = lane
__global__ __launch_bounds__(256) void k_conv1L(
    const int* __restrict__ target,
    const void* g, const void* be, const void* m, const void* v, int obn)
{
    const int F = g_isf32;
    __shared__ float sP[16*26*32];
    __shared__ int   stg[LSEQ];
    __shared__ float sxb[32], sA[32], sB[32];
    int b = blockIdx.x, tid = threadIdx.x;
    for (int i = tid; i < 16*26*32; i += 256) sP[i] = g_P[i];
    for (int i = tid; i < LSEQ; i += 256) stg[i] = target[b*LSEQ + i];
    if (tid < 32){
        sxb[tid] = g_xdb[b*32 + tid];
        float inv = LD(g, obn + tid, F) * rsqrtf(LD(v, obn + tid, F) + BN_EPS);
        sA[tid] = inv;
        sB[tid] = LD(be, obn + tid, F) - LD(m, obn + tid, F) * inv;
    }
    __syncthreads();
    int o = tid & 31, wsub = tid >> 5;
    float xb = sxb[o], aa = sA[o], bb = sB[o];
    for (int w = wsub; w < W1O; w += 8){
        float a = xb;
        #pragma unroll
        for (int k = 0; k < 16; k++)
            a += sP[(k*26 + stg[w + k])*32 + o];
        g_c1o[(b*32 + o)*C1S + w] = fmaxf(a * aa + bb, 0.f);
    }
}

// ---------------- conv2/conv3 via MFMA, double-bf16 split (f32-accurate) ------
// r10 structure with 2-tap weight passes: LDS 33.8 KB -> 4 blocks/CU
// (16 waves, was 12). Accumulation order ktg = 0..15 unchanged -> bit-identical.

#define CT_W 128
#define CT_R 144     // 128 + 15 halo, padded
#define CPAD 40      // c-row pad: 80 B = 16B-aligned rows, 2-way bank alias (free)

__global__ __launch_bounds__(256) void k_cmfma(
    int sel, int Wvalid, int Wout, int inStride,
    const void* bias, const void* g, const void* be,
    const void* m, const void* v, int obn)
{
    const int F = g_isf32;
    const float* in = (sel == 0) ? g_c1o : g_c2o;
    __shared__ __attribute__((aligned(16))) unsigned short sAh[CT_R*CPAD]; // 11520 B
    __shared__ __attribute__((aligned(16))) unsigned short sAl[CT_R*CPAD]; // 11520 B
    __shared__ __attribute__((aligned(16))) unsigned short sBh[2*32*CPAD]; //  5120 B
    __shared__ __attribute__((aligned(16))) unsigned short sBl[2*32*CPAD]; //  5120 B
    __shared__ float sSc[32], sOf[32];
    int tid = threadIdx.x;
    int b = blockIdx.x >> 3;
    int tile = blockIdx.x & 7;
    int wbase = tile * CT_W;

    // stage input tile (hi/lo split); coalesced along w per channel row
    for (int c = 0; c < 32; c++){
        const float* src = in + (b*32 + c)*inStride;
        if (tid < CT_R){
            int wg_ = wbase + tid;
            float xv = (wg_ < Wvalid) ? src[wg_] : 0.f;
            unsigned short h = f2b(xv);
            sAh[tid*CPAD + c] = h;
            sAl[tid*CPAD + c] = f2b(xv - bb2f(h));
        }
    }
    if (tid < 32){
        float inv = LD(g, obn + tid, F) * rsqrtf(LD(v, obn + tid, F) + BN_EPS);
        sSc[tid] = inv;
        sOf[tid] = LD(be, obn + tid, F) + (LD(bias, tid, F) - LD(m, obn + tid, F)) * inv;
    }

    int lane = tid & 63;
    int wv = tid >> 6;
    int ml = lane & 15, quad = lane >> 4;
    int wgrp = wv & 1;           // w-half: 0 -> w 0..63, 1 -> 64..127
    int ogrp = wv >> 1;          // o-half: o = ml + ogrp*16

    const unsigned short* wph = &g_wph[sel][0];
    const unsigned short* wpl = &g_wpl[sel][0];

    f4v acc[4];
    #pragma unroll
    for (int mt = 0; mt < 4; mt++) acc[mt] = (f4v){0.f, 0.f, 0.f, 0.f};

    for (int kp = 0; kp < 8; kp++){
        __syncthreads();         // sA visible (kp=0) / previous-pass B reads done
        // stage 2-tap weight block: LINEAR coalesced u16 reads, LDS writes
        // c-fastest (2 lanes/dword-bank = free)
        for (int i = tid; i < 2048; i += 256){
            int c = i & 31, o = (i >> 5) & 31, kt2 = i >> 10;
            int ldsi = (kt2*32 + o)*CPAD + c;
            sBh[ldsi] = wph[kp*2048 + i];
            sBl[ldsi] = wpl[kp*2048 + i];
        }
        __syncthreads();
        for (int kt = 0; kt < 2; kt++){
            int ktg = kp*2 + kt;
            const int bidx = (kt*32 + ogrp*16 + ml)*CPAD + quad*8;
            s8v bh = *(const s8v*)&sBh[bidx];
            s8v bl = *(const s8v*)&sBl[bidx];
            #pragma unroll
            for (int mt = 0; mt < 4; mt++){
                int row = wgrp*64 + mt*16 + ml + ktg;
                const int aidx = row*CPAD + quad*8;
                s8v ah = *(const s8v*)&sAh[aidx];
                s8v al = *(const s8v*)&sAl[aidx];
                acc[mt] = __builtin_amdgcn_mfma_f32_16x16x32_bf16(ah, bh, acc[mt], 0, 0, 0);
                acc[mt] = __builtin_amdgcn_mfma_f32_16x16x32_bf16(ah, bl, acc[mt], 0, 0, 0);
                acc[mt] = __builtin_amdgcn_mfma_f32_16x16x32_bf16(al, bh, acc[mt], 0, 0, 0);
            }
        }
    }

    int o = ogrp*16 + ml;
    float sc = sSc[o], of = sOf[o];
    #pragma unroll
    for (int mt = 0; mt < 4; mt++){
        int w0 = wbase + wgrp*64 + mt*16 + quad*4;
        f4v a = acc[mt];
        float y0 = fmaxf(a.x*sc + of, 0.f);
        float y1 = fmaxf(a.y*sc + of, 0.f);
        float y2 = fmaxf(a.z*sc + of, 0.f);
        float y3 = fmaxf(a.w*sc + of, 0.f);
        if (sel == 0){
            float* dst = &g_c2o[(b*32 + o)*C2S + w0];
            if (w0 + 3 < Wout){
                *(float4*)dst = make_float4(y0, y1, y2, y3);
            } else if (w0 < Wout){
                dst[0] = y0;
                if (w0+1 < Wout) dst[1] = y1;
                if (w0+2 < Wout) dst[2] = y2;
                if (w0+3 < Wout) dst[3] = y3;
            }
        } else {
            if (w0 < Wout){
                float mx = y0;
                if (w0+1 < Wout) mx = fmaxf(mx, y1);
                if (w0+2 < Wout) mx = fmaxf(mx, y2);
                if (w0+3 < Wout) mx = fmaxf(mx, y3);
                atomicMax((int*)&g_xcm[b*32 + o], __float_as_int(mx));
            }
        }
    }
}

// ---------------- FC tail ----------------

__global__ void k_xcf(const void* W, const void* bias,
                      const void* g, const void* be, const void* m, const void* v){
    const int F = g_isf32;
    __shared__ float sp[32];
    int b = blockIdx.x, j = threadIdx.x;
    if (j < 32) sp[j] = g_xcm[b*32 + j];
    __syncthreads();
    float a = LD(bias, j, F);
    #pragma unroll
    for (int i = 0; i < 32; i++) a += sp[i] * LD(W, i*128 + j, F);
    float inv = LD(g, j, F) * rsqrtf(LD(v, j, F) + BN_EPS);
    a = (a - LD(m, j, F)) * inv + LD(be, j, F);
    g_xcf[b*128 + j] = fmaxf(a, 0.f);
}

__global__ __launch_bounds__(256) void k_fc1(const void* W, const void* bias){
    const int F = g_isf32;
    __shared__ float sz[256];
    int b = blockIdx.x >> 2;
    int j = ((blockIdx.x & 3) << 8) + threadIdx.x;
    int t = threadIdx.x;
    sz[t] = (t < 128) ? g_xd[b*128 + t] : g_xcf[b*128 + (t - 128)];
    __syncthreads();
    float a = LD(bias, j, F);
    for (int i = 0; i < 256; i++) a += sz[i] * LD(W, i*1024 + j, F);
    g_z1[b*1024 + j] = fmaxf(a, 0.f);
}

// 1024 threads: 4-way K-split + LDS reduce (16 waves/CU vs 4 -> latency hidden)
__global__ __launch_bounds__(1024) void k_fc2(const void* W, const void* bias){
    const int F = g_isf32;
    __shared__ float sz[1024];
    __shared__ float sp[4][256];
    int b = blockIdx.x, t = threadIdx.x;
    sz[t] = g_z1[b*1024 + t];
    __syncthreads();
    int j = t & 255, kq = t >> 8;
    float a = 0.f;
    #pragma unroll 8
    for (int i = 0; i < 256; i++)
        a += sz[kq*256 + i] * LD(W, (kq*256 + i)*256 + j, F);
    sp[kq][j] = a;
    __syncthreads();
    if (t < 256){
        float r = sp[0][t] + sp[1][t] + sp[2][t] + sp[3][t] + LD(bias, t, F);
        g_z2[b*256 + t] = fmaxf(r, 0.f);
    }
}

__global__ void k_out(const void* W, const void* bias, void* out){
    const int F = g_isf32;
    __shared__ float red[256];
    int b = blockIdx.x, t = threadIdx.x;
    red[t] = g_z2[b*256 + t] * LD(W, t, F);
    __syncthreads();
    for (int s = 128; s > 0; s >>= 1){
        if (t < s) red[t] += red[t + s];
        __syncthreads();
    }
    if (t == 0){
        float r = red[0] + LD(bias, 0, F);
        if (F) ((float*)out)[b] = r;
        else   ((bf16*)out)[b] = __float2bfloat16(r);
    }
}

// ---------------- launch ----------------

extern "C" void kernel_launch(void* const* d_in, const int* in_sizes, int n_in,
                              void* d_out, int out_size, void* d_ws, size_t ws_size,
                              hipStream_t stream)
{
    (void)in_sizes; (void)n_in; (void)out_size; (void)d_ws; (void)ws_size;
    const void* x      = d_in[0];
    const int*  ei     = (const int*)d_in[1];
    const int*  batch  = (const int*)d_in[2];
    const int*  target = (const int*)d_in[3];
    const void* g1W1 = d_in[4];  const void* g1b1 = d_in[5];
    const void* g1W2 = d_in[6];  const void* g1b2 = d_in[7];
    const void* gW1  = d_in[8];  const void* gb1  = d_in[9];
    const void* gW2  = d_in[10]; const void* gb2  = d_in[11];
    const void* bng  = d_in[12]; const void* bnb  = d_in[13];
    const void* bnm  = d_in[14]; const void* bnv  = d_in[15];
    const void* fcxdW = d_in[16]; const void* fcxdb = d_in[17];
    const void* embed = d_in[18];
    const void* c1W = d_in[19]; const void* c1b = d_in[20];
    const void* c2W = d_in[21]; const void* c2b = d_in[22];
    const void* c3W = d_in[23]; const void* c3b = d_in[24];
    const void* cbng = d_in[25]; const void* cbnb = d_in[26];
    const void* cbnm = d_in[27]; const void* cbnv = d_in[28];
    const void* fcxcW = d_in[29]; const void* fcxcb = d_in[30];
    const void* bnfcg = d_in[31]; const void* bnfcb = d_in[32];
    const void* bnfcm = d_in[33]; const void* bnfcv = d_in[34];
    const void* fc1W = d_in[35]; const void* fc1b = d_in[36];
    const void* fc2W = d_in[37]; const void* fc2b = d_in[38];
    const void* outW = d_in[39]; const void* outb = d_in[40];

    k_dtype<<<1, 64, 0, stream>>>(x);
    k_wpack<<<128, 256, 0, stream>>>(c2W, c3W);

    // ---- GIN layer 1 (projected scatter) ----
    k_proj78<<<N_NODES/8, 256, 0, stream>>>(x, g1W1);
    k_zero_agg<<<N_NODES*32/256, 256, 0, stream>>>();
    k_zero_misc<<<NB*32/256, 256, 0, stream>>>();
    k_scatter32<<<(N_EDGES*32)/256, 256, 0, stream>>>(ei);
    k_gin1b<<<N_NODES/8, 256, 0, stream>>>(g1b1, g1W2, g1b2, bng, bnb, bnm, bnv);
    // ---- GIN layers 2..5 (agg re-zeroed inside the previous gin kernel) ----
    for (int l = 0; l < 4; l++){
        k_scatter32<<<(N_EDGES*32)/256, 256, 0, stream>>>(ei);
        k_gin32L<<<N_NODES/8, 256, 0, stream>>>(gW1, gb1, gW2, gb2,
                                                bng, bnb, bnm, bnv, l);
    }
    // ---- pool + xd ----
    k_pool<<<(N_NODES*32)/256, 256, 0, stream>>>(batch);
    k_xd<<<NB, 128, 0, stream>>>(fcxdW, fcxdb);
    // ---- conv1 prep ----
    k_P<<<(16*26*32 + 255)/256, 256, 0, stream>>>(embed, c1W);
    k_wsum<<<16, 256, 0, stream>>>(c1W);
    k_xdbias<<<32, 256, 0, stream>>>(c1b);
    // ---- conv chain ----
    k_conv1L<<<NB, 256, 0, stream>>>(target, cbng, cbnb, cbnm, cbnv, 0);
    k_cmfma<<<NB*8, 256, 0, stream>>>(0, W1O, W2O, C1S,
                                      c2b, cbng, cbnb, cbnm, cbnv, 32);
    k_cmfma<<<NB*8, 256, 0, stream>>>(1, W2O, W3O, C2S,
                                      c3b, cbng, cbnb, cbnm, cbnv, 64);
    // ---- FC tail ----
    k_xcf<<<NB, 128, 0, stream>>>(fcxcW, fcxcb, bnfcg, bnfcb, bnfcm, bnfcv);
    k_fc1<<<NB*4, 256, 0, stream>>>(fc1W, fc1b);
    k_fc2<<<NB, 1024, 0, stream>>>(fc2W, fc2b);
    k_out<<<NB, 256, 0, stream>>>(outW, outb, d_out);
}

// Round 12
// 506.277 us; speedup vs baseline: 4.3046x; 1.0714x over previous
//
#include <hip/hip_runtime.h>
#include <hip/hip_bf16.h>

typedef __hip_bfloat16 bf16;
__device__ __forceinline__ float b2f(bf16 v){ return __bfloat162float(v); }

typedef __attribute__((ext_vector_type(8))) short s8v;
typedef __attribute__((ext_vector_type(4))) float f4v;

#define N_NODES 16384
#define N_EDGES 65536
#define NB 256
#define LSEQ 1000
#define BN_EPS 1e-5f
#define W1O 985
#define W2O 970
#define W3O 955
#define C1S 988          // g_c1o row stride (floats), layout [b][32 ch][C1S]
#define C2S 976          // g_c2o row stride (floats), layout [b][32 ch][C2S]

// ---- dtype flag: 1 if float inputs are f32, 0 if bf16 (measured: f32 on this harness) ----
__device__ int g_isf32;

__device__ __forceinline__ float LD(const void* p, int i, int f){
    return f ? ((const float*)p)[i] : b2f(((const bf16*)p)[i]);
}

// f32 -> bf16 bits, round-to-nearest-even
__device__ __forceinline__ unsigned short f2b(float x){
    unsigned u = __float_as_uint(x);
    return (unsigned short)((u + 0x7FFFu + ((u >> 16) & 1u)) >> 16);
}
__device__ __forceinline__ float bb2f(unsigned short h){
    return __uint_as_float(((unsigned)h) << 16);
}

__global__ void k_dtype(const void* x){
    if (threadIdx.x != 0 || blockIdx.x != 0) return;
    const unsigned short* u = (const unsigned short*)x;
    int insane = 0;
    for (int i = 0; i < 512; i++){
        unsigned short h = u[i];
        int ex = (h >> 7) & 0xFF;
        if (!(h == 0 || (ex >= 96 && ex <= 142))) insane++;
    }
    g_isf32 = (insane > 50) ? 1 : 0;
}

// ---- intermediates in device globals ----
__device__ float g_hA[N_NODES*32];
__device__ float g_agg[N_NODES*32];
__device__ float g_pooled[NB*32];
__device__ float g_xd[NB*128];
__device__ float g_P[16*26*32];
__device__ float g_wsum[32*128];
__device__ float g_xdb[NB*32];
__device__ float g_xcm[NB*32];
__device__ float g_xcf[NB*128];
__device__ float g_z1[NB*1024];
__device__ float g_z2[NB*256];
__device__ float g_c1o[NB*32*C1S];   // 32.4 MB, [b][o][w]
__device__ float g_c2o[NB*32*C2S];   // 32.0 MB, [b][o][w]
// pre-packed conv weights in per-lane B-FRAGMENT order (s8v granularity):
// s8v index = ktg*256 + ogrp*128 + hl*64 + lane ; lane holds
// W[c=quad*8+j][o=ogrp*16+ml] for j=0..7  (hl: 0=hi, 1=lo bf16 split)
__device__ __attribute__((aligned(16))) unsigned short g_wf[2][32768];

__global__ void k_zero_agg(){ g_agg[blockIdx.x*256 + threadIdx.x] = 0.f; }
__global__ void k_zero_misc(){
    int i = blockIdx.x*256 + threadIdx.x;
    g_pooled[i] = 0.f;
    g_xcm[i] = 0.f;
}

// ---- weight pre-pack into fragment order: scattered reads once, coalesced writes ----
__global__ void k_wpack(const void* w2, const void* w3){
    const int F = g_isf32;
    int idx = blockIdx.x*256 + threadIdx.x;      // 65536 threads
    int sel = idx >> 15;
    int r = idx & 32767;
    int j = r & 7;
    int lane = (r >> 3) & 63;
    int hl = (r >> 9) & 1;
    int ogrp = (r >> 10) & 1;
    int ktg = r >> 11;                           // 0..15
    int c = (lane >> 4)*8 + j;
    int o = ogrp*16 + (lane & 15);
    const void* Wt = sel ? w3 : w2;
    float wv = LD(Wt, o*512 + c*16 + ktg, F);
    unsigned short h = f2b(wv);
    g_wf[sel][r] = hl ? f2b(wv - bb2f(h)) : h;
}

// ---------------- GIN branch ----------------

__global__ __launch_bounds__(256) void k_proj78(const void* x, const void* W1)
{
    const int F = g_isf32;
    __shared__ float sW1[78*32];
    __shared__ float sx[8][78];
    int tid = threadIdx.x;
    for (int i = tid; i < 78*32; i += 256) sW1[i] = LD(W1, i, F);
    int nodeBase = blockIdx.x * 8;
    for (int i = tid; i < 8*78; i += 256){
        int ln = i / 78, f = i - ln*78;
        sx[ln][f] = LD(x, (nodeBase + ln)*78 + f, F);
    }
    __syncthreads();
    int ln = tid >> 5, j = tid & 31;
    float a = 0.f;
    #pragma unroll 6
    for (int i = 0; i < 78; i++) a += sx[ln][i] * sW1[i*32 + j];
    g_hA[(nodeBase + ln)*32 + j] = a;
}

__global__ void k_scatter32(const int* __restrict__ ei){
    int idx = blockIdx.x*256 + threadIdx.x;
    int e = idx >> 5, f = idx & 31;
    atomicAdd(&g_agg[ei[N_EDGES + e]*32 + f], g_hA[ei[e]*32 + f]);
}

// also zeroes g_agg for the next layer's scatter (same thread, same location)
__global__ __launch_bounds__(256) void k_gin1b(
    const void* b1, const void* W2, const void* b2,
    const void* bng, const void* bnb, const void* bnm, const void* bnv)
{
    const int F = g_isf32;
    __shared__ float sW2[32*32];
    __shared__ float sb1[32], sb2[32], sA[32], sB[32];
    __shared__ float st[8][32];
    int tid = threadIdx.x;
    for (int i = tid; i < 1024; i += 256) sW2[i] = LD(W2, i, F);
    if (tid < 32){
        sb1[tid] = LD(b1, tid, F); sb2[tid] = LD(b2, tid, F);
        float inv = LD(bng, tid, F) * rsqrtf(LD(bnv, tid, F) + BN_EPS);
        sA[tid] = inv;
        sB[tid] = LD(bnb, tid, F) - LD(bnm, tid, F) * inv;
    }
    __syncthreads();
    int ln = tid >> 5, j = tid & 31;
    int n = blockIdx.x*8 + ln;
    st[ln][j] = fmaxf(g_hA[n*32 + j] + g_agg[n*32 + j] + sb1[j], 0.f);
    g_agg[n*32 + j] = 0.f;
    __syncthreads();
    float t2 = sb2[j];
    #pragma unroll
    for (int i = 0; i < 32; i++) t2 += st[ln][i] * sW2[i*32 + j];
    t2 = fmaxf(t2, 0.f);
    g_hA[n*32 + j] = t2 * sA[j] + sB[j];
}

__global__ __launch_bounds__(256) void k_gin32L(
    const void* W1, const void* b1, const void* W2, const void* b2,
    const void* bng, const void* bnb, const void* bnm, const void* bnv, int l)
{
    const int F = g_isf32;
    const int oW = l*1024, ob = l*32, obn = (l+1)*32;
    __shared__ float sW1[32*32], sW2[32*32];
    __shared__ float sb1[32], sb2[32], sA[32], sB[32];
    __shared__ float sh[8][32], st[8][32];
    int tid = threadIdx.x;
    for (int i = tid; i < 1024; i += 256){ sW1[i] = LD(W1, oW + i, F); sW2[i] = LD(W2, oW + i, F); }
    if (tid < 32){
        sb1[tid] = LD(b1, ob + tid, F); sb2[tid] = LD(b2, ob + tid, F);
        float inv = LD(bng, obn + tid, F) * rsqrtf(LD(bnv, obn + tid, F) + BN_EPS);
        sA[tid] = inv;
        sB[tid] = LD(bnb, obn + tid, F) - LD(bnm, obn + tid, F) * inv;
    }
    int ln = tid >> 5, j = tid & 31;
    int n = blockIdx.x*8 + ln;
    sh[ln][j] = g_hA[n*32 + j] + g_agg[n*32 + j];
    g_agg[n*32 + j] = 0.f;
    __syncthreads();
    float t1 = sb1[j];
    #pragma unroll
    for (int i = 0; i < 32; i++) t1 += sh[ln][i] * sW1[i*32 + j];
    st[ln][j] = fmaxf(t1, 0.f);
    __syncthreads();
    float t2 = sb2[j];
    #pragma unroll
    for (int i = 0; i < 32; i++) t2 += st[ln][i] * sW2[i*32 + j];
    t2 = fmaxf(t2, 0.f);
    g_hA[n*32 + j] = t2 * sA[j] + sB[j];
}

__global__ void k_pool(const int* __restrict__ batch){
    int idx = blockIdx.x*256 + threadIdx.x;
    int n = idx >> 5;
    atomicAdd(&g_pooled[batch[n]*32 + (idx & 31)], g_hA[idx]);
}

__global__ void k_xd(const void* W, const void* bias){
    const int F = g_isf32;
    __shared__ float sp[32];
    int b = blockIdx.x, j = threadIdx.x;
    if (j < 32) sp[j] = g_pooled[b*32 + j];
    __syncthreads();
    float a = LD(bias, j, F);
    #pragma unroll
    for (int i = 0; i < 32; i++) a += sp[i] * LD(W, i*128 + j, F);
    g_xd[b*128 + j] = fmaxf(a, 0.f);
}

// ---------------- conv1 via 26-row embedding table ----------------

__global__ void k_P(const void* embed, const void* c1W){
    const int F = g_isf32;
    int idx = blockIdx.x*256 + threadIdx.x;
    if (idx >= 16*26*32) return;
    int o = idx & 31;
    int t = (idx >> 5) % 26;
    int k = idx / (32*26);
    float a = 0.f;
    for (int c = 0; c < 128; c++)
        a += LD(embed, t*128 + c, F) * LD(c1W, o*4096 + c*16 + k, F);
    g_P[(k*26 + t)*32 + o] = a;
}

__global__ void k_wsum(const void* c1W){
    const int F = g_isf32;
    int idx = blockIdx.x*256 + threadIdx.x;
    int o = idx >> 7, c = idx & 127;
    float a = 0.f;
    #pragma unroll
    for (int k = 0; k < 16; k++) a += LD(c1W, o*4096 + (128 + c)*16 + k, F);
    g_wsum[o*128 + c] = a;
}

__global__ void k_xdbias(const void* c1b){
    const int F = g_isf32;
    int idx = blockIdx.x*256 + threadIdx.x;
    int b = idx >> 5, o = idx & 31;
    float a = LD(c1b, o, F);
    for (int c = 0; c < 128; c++) a += g_xd[b*128 + c] * g_wsum[o*128 + c];
    g_xdb[idx] = a;
}

// writes [b][o][w] layout (stride C1S). o = tid&31 -> table-gather bank = lane
__global__ __launch_bounds__(256) void k_conv1L(
    const int* __restrict__ target,
    const void* g, const void* be, const void* m, const void* v, int obn)
{
    const int F = g_isf32;
    __shared__ float sP[16*26*32];
    __shared__ int   stg[LSEQ];
    __shared__ float sxb[32], sA[32], sB[32];
    int b = blockIdx.x, tid = threadIdx.x;
    for (int i = tid; i < 16*26*32; i += 256) sP[i] = g_P[i];
    for (int i = tid; i < LSEQ; i += 256) stg[i] = target[b*LSEQ + i];
    if (tid < 32){
        sxb[tid] = g_xdb[b*32 + tid];
        float inv = LD(g, obn + tid, F) * rsqrtf(LD(v, obn + tid, F) + BN_EPS);
        sA[tid] = inv;
        sB[tid] = LD(be, obn + tid, F) - LD(m, obn + tid, F) * inv;
    }
    __syncthreads();
    int o = tid & 31, wsub = tid >> 5;
    float xb = sxb[o], aa = sA[o], bb = sB[o];
    for (int w = wsub; w < W1O; w += 8){
        float a = xb;
        #pragma unroll
        for (int k = 0; k < 16; k++)
            a += sP[(k*26 + stg[w + k])*32 + o];
        g_c1o[(b*32 + o)*C1S + w] = fmaxf(a * aa + bb, 0.f);
    }
}

// ---------------- conv2/conv3 via MFMA, double-bf16 split (f32-accurate) ------
// r11 structure minus the LDS weight machinery: B-fragments are read from
// g_wf (per-lane fragment order, coalesced L2-hot dwordx4) with a 1-tap
// register prefetch. ONE barrier per block (after A staging); LDS 23.3 KB.
// Accumulation order ktg = 0..15 unchanged -> bit-identical to r10/r11.

#define CT_W 128
#define CT_R 144     // 128 + 15 halo, padded
#define CPAD 40      // c-row pad: 80 B = 16B-aligned rows, 2-way bank alias (free)

__global__ __launch_bounds__(256) void k_cmfma(
    int sel, int Wvalid, int Wout, int inStride,
    const void* bias, const void* g, const void* be,
    const void* m, const void* v, int obn)
{
    const int F = g_isf32;
    const float* in = (sel == 0) ? g_c1o : g_c2o;
    __shared__ __attribute__((aligned(16))) unsigned short sAh[CT_R*CPAD]; // 11520 B
    __shared__ __attribute__((aligned(16))) unsigned short sAl[CT_R*CPAD]; // 11520 B
    __shared__ float sSc[32], sOf[32];
    int tid = threadIdx.x;
    int b = blockIdx.x >> 3;
    int tile = blockIdx.x & 7;
    int wbase = tile * CT_W;

    // stage input tile (hi/lo split); coalesced along w per channel row
    for (int c = 0; c < 32; c++){
        const float* src = in + (b*32 + c)*inStride;
        if (tid < CT_R){
            int wg_ = wbase + tid;
            float xv = (wg_ < Wvalid) ? src[wg_] : 0.f;
            unsigned short h = f2b(xv);
            sAh[tid*CPAD + c] = h;
            sAl[tid*CPAD + c] = f2b(xv - bb2f(h));
        }
    }
    if (tid < 32){
        float inv = LD(g, obn + tid, F) * rsqrtf(LD(v, obn + tid, F) + BN_EPS);
        sSc[tid] = inv;
        sOf[tid] = LD(be, obn + tid, F) + (LD(bias, tid, F) - LD(m, obn + tid, F)) * inv;
    }
    __syncthreads();                 // the ONLY barrier

    int lane = tid & 63;
    int wv = tid >> 6;
    int ml = lane & 15, quad = lane >> 4;
    int wgrp = wv & 1;           // w-half: 0 -> w 0..63, 1 -> 64..127
    int ogrp = wv >> 1;          // o-half: o = ml + ogrp*16

    // per-wave B-fragment stream: s8v index = ktg*256 + ogrp*128 + hl*64 + lane
    const s8v* wfb = (const s8v*)&g_wf[sel][0] + ogrp*128 + lane;

    f4v acc[4];
    #pragma unroll
    for (int mt = 0; mt < 4; mt++) acc[mt] = (f4v){0.f, 0.f, 0.f, 0.f};

    s8v nbh = wfb[0], nbl = wfb[64];     // prefetch tap 0
    for (int ktg = 0; ktg < 16; ktg++){
        s8v bh = nbh, bl = nbl;
        if (ktg < 15){
            nbh = wfb[(ktg + 1)*256];
            nbl = wfb[(ktg + 1)*256 + 64];
        }
        #pragma unroll
        for (int mt = 0; mt < 4; mt++){
            int row = wgrp*64 + mt*16 + ml + ktg;
            const int aidx = row*CPAD + quad*8;
            s8v ah = *(const s8v*)&sAh[aidx];
            s8v al = *(const s8v*)&sAl[aidx];
            acc[mt] = __builtin_amdgcn_mfma_f32_16x16x32_bf16(ah, bh, acc[mt], 0, 0, 0);
            acc[mt] = __builtin_amdgcn_mfma_f32_16x16x32_bf16(ah, bl, acc[mt], 0, 0, 0);
            acc[mt] = __builtin_amdgcn_mfma_f32_16x16x32_bf16(al, bh, acc[mt], 0, 0, 0);
        }
    }

    int o = ogrp*16 + ml;
    float sc = sSc[o], of = sOf[o];
    #pragma unroll
    for (int mt = 0; mt < 4; mt++){
        int w0 = wbase + wgrp*64 + mt*16 + quad*4;
        f4v a = acc[mt];
        float y0 = fmaxf(a.x*sc + of, 0.f);
        float y1 = fmaxf(a.y*sc + of, 0.f);
        float y2 = fmaxf(a.z*sc + of, 0.f);
        float y3 = fmaxf(a.w*sc + of, 0.f);
        if (sel == 0){
            float* dst = &g_c2o[(b*32 + o)*C2S + w0];
            if (w0 + 3 < Wout){
                *(float4*)dst = make_float4(y0, y1, y2, y3);
            } else if (w0 < Wout){
                dst[0] = y0;
                if (w0+1 < Wout) dst[1] = y1;
                if (w0+2 < Wout) dst[2] = y2;
                if (w0+3 < Wout) dst[3] = y3;
            }
        } else {
            if (w0 < Wout){
                float mx = y0;
                if (w0+1 < Wout) mx = fmaxf(mx, y1);
                if (w0+2 < Wout) mx = fmaxf(mx, y2);
                if (w0+3 < Wout) mx = fmaxf(mx, y3);
                atomicMax((int*)&g_xcm[b*32 + o], __float_as_int(mx));
            }
        }
    }
}

// ---------------- FC tail ----------------

__global__ void k_xcf(const void* W, const void* bias,
                      const void* g, const void* be, const void* m, const void* v){
    const int F = g_isf32;
    __shared__ float sp[32];
    int b = blockIdx.x, j = threadIdx.x;
    if (j < 32) sp[j] = g_xcm[b*32 + j];
    __syncthreads();
    float a = LD(bias, j, F);
    #pragma unroll
    for (int i = 0; i < 32; i++) a += sp[i] * LD(W, i*128 + j, F);
    float inv = LD(g, j, F) * rsqrtf(LD(v, j, F) + BN_EPS);
    a = (a - LD(m, j, F)) * inv + LD(be, j, F);
    g_xcf[b*128 + j] = fmaxf(a, 0.f);
}

__global__ __launch_bounds__(256) void k_fc1(const void* W, const void* bias){
    const int F = g_isf32;
    __shared__ float sz[256];
    int b = blockIdx.x >> 2;
    int j = ((blockIdx.x & 3) << 8) + threadIdx.x;
    int t = threadIdx.x;
    sz[t] = (t < 128) ? g_xd[b*128 + t] : g_xcf[b*128 + (t - 128)];
    __syncthreads();
    float a = LD(bias, j, F);
    for (int i = 0; i < 256; i++) a += sz[i] * LD(W, i*1024 + j, F);
    g_z1[b*1024 + j] = fmaxf(a, 0.f);
}

// 1024 threads: 4-way K-split + LDS reduce (16 waves/CU vs 4 -> latency hidden)
__global__ __launch_bounds__(1024) void k_fc2(const void* W, const void* bias){
    const int F = g_isf32;
    __shared__ float sz[1024];
    __shared__ float sp[4][256];
    int b = blockIdx.x, t = threadIdx.x;
    sz[t] = g_z1[b*1024 + t];
    __syncthreads();
    int j = t & 255, kq = t >> 8;
    float a = 0.f;
    #pragma unroll 8
    for (int i = 0; i < 256; i++)
        a += sz[kq*256 + i] * LD(W, (kq*256 + i)*256 + j, F);
    sp[kq][j] = a;
    __syncthreads();
    if (t < 256){
        float r = sp[0][t] + sp[1][t] + sp[2][t] + sp[3][t] + LD(bias, t, F);
        g_z2[b*256 + t] = fmaxf(r, 0.f);
    }
}

__global__ void k_out(const void* W, const void* bias, void* out){
    const int F = g_isf32;
    __shared__ float red[256];
    int b = blockIdx.x, t = threadIdx.x;
    red[t] = g_z2[b*256 + t] * LD(W, t, F);
    __syncthreads();
    for (int s = 128; s > 0; s >>= 1){
        if (t < s) red[t] += red[t + s];
        __syncthreads();
    }
    if (t == 0){
        float r = red[0] + LD(bias, 0, F);
        if (F) ((float*)out)[b] = r;
        else   ((bf16*)out)[b] = __float2bfloat16(r);
    }
}

// ---------------- launch ----------------

extern "C" void kernel_launch(void* const* d_in, const int* in_sizes, int n_in,
                              void* d_out, int out_size, void* d_ws, size_t ws_size,
                              hipStream_t stream)
{
    (void)in_sizes; (void)n_in; (void)out_size; (void)d_ws; (void)ws_size;
    const void* x      = d_in[0];
    const int*  ei     = (const int*)d_in[1];
    const int*  batch  = (const int*)d_in[2];
    const int*  target = (const int*)d_in[3];
    const void* g1W1 = d_in[4];  const void* g1b1 = d_in[5];
    const void* g1W2 = d_in[6];  const void* g1b2 = d_in[7];
    const void* gW1  = d_in[8];  const void* gb1  = d_in[9];
    const void* gW2  = d_in[10]; const void* gb2  = d_in[11];
    const void* bng  = d_in[12]; const void* bnb  = d_in[13];
    const void* bnm  = d_in[14]; const void* bnv  = d_in[15];
    const void* fcxdW = d_in[16]; const void* fcxdb = d_in[17];
    const void* embed = d_in[18];
    const void* c1W = d_in[19]; const void* c1b = d_in[20];
    const void* c2W = d_in[21]; const void* c2b = d_in[22];
    const void* c3W = d_in[23]; const void* c3b = d_in[24];
    const void* cbng = d_in[25]; const void* cbnb = d_in[26];
    const void* cbnm = d_in[27]; const void* cbnv = d_in[28];
    const void* fcxcW = d_in[29]; const void* fcxcb = d_in[30];
    const void* bnfcg = d_in[31]; const void* bnfcb = d_in[32];
    const void* bnfcm = d_in[33]; const void* bnfcv = d_in[34];
    const void* fc1W = d_in[35]; const void* fc1b = d_in[36];
    const void* fc2W = d_in[37]; const void* fc2b = d_in[38];
    const void* outW = d_in[39]; const void* outb = d_in[40];

    k_dtype<<<1, 64, 0, stream>>>(x);
    k_wpack<<<256, 256, 0, stream>>>(c2W, c3W);

    // ---- GIN layer 1 (projected scatter) ----
    k_proj78<<<N_NODES/8, 256, 0, stream>>>(x, g1W1);
    k_zero_agg<<<N_NODES*32/256, 256, 0, stream>>>();
    k_zero_misc<<<NB*32/256, 256, 0, stream>>>();
    k_scatter32<<<(N_EDGES*32)/256, 256, 0, stream>>>(ei);
    k_gin1b<<<N_NODES/8, 256, 0, stream>>>(g1b1, g1W2, g1b2, bng, bnb, bnm, bnv);
    // ---- GIN layers 2..5 (agg re-zeroed inside the previous gin kernel) ----
    for (int l = 0; l < 4; l++){
        k_scatter32<<<(N_EDGES*32)/256, 256, 0, stream>>>(ei);
        k_gin32L<<<N_NODES/8, 256, 0, stream>>>(gW1, gb1, gW2, gb2,
                                                bng, bnb, bnm, bnv, l);
    }
    // ---- pool + xd ----
    k_pool<<<(N_NODES*32)/256, 256, 0, stream>>>(batch);
    k_xd<<<NB, 128, 0, stream>>>(fcxdW, fcxdb);
    // ---- conv1 prep ----
    k_P<<<(16*26*32 + 255)/256, 256, 0, stream>>>(embed, c1W);
    k_wsum<<<16, 256, 0, stream>>>(c1W);
    k_xdbias<<<32, 256, 0, stream>>>(c1b);
    // ---- conv chain ----
    k_conv1L<<<NB, 256, 0, stream>>>(target, cbng, cbnb, cbnm, cbnv, 0);
    k_cmfma<<<NB*8, 256, 0, stream>>>(0, W1O, W2O, C1S,
                                      c2b, cbng, cbnb, cbnm, cbnv, 32);
    k_cmfma<<<NB*8, 256, 0, stream>>>(1, W2O, W3O, C2S,
                                      c3b, cbng, cbnb, cbnm, cbnv, 64);
    // ---- FC tail ----
    k_xcf<<<NB, 128, 0, stream>>>(fcxcW, fcxcb, bnfcg, bnfcb, bnfcm, bnfcv);
    k_fc1<<<NB*4, 256, 0, stream>>>(fc1W, fc1b);
    k_fc2<<<NB, 1024, 0, stream>>>(fc2W, fc2b);
    k_out<<<NB, 256, 0, stream>>>(outW, outb, d_out);
}

// Round 13
// 492.285 us; speedup vs baseline: 4.4269x; 1.0284x over previous
//
#include <hip/hip_runtime.h>
#include <hip/hip_bf16.h>

typedef __hip_bfloat16 bf16;
__device__ __forceinline__ float b2f(bf16 v){ return __bfloat162float(v); }

typedef __attribute__((ext_vector_type(8))) short s8v;
typedef __attribute__((ext_vector_type(4))) float f4v;

#define N_NODES 16384
#define N_EDGES 65536
#define NB 256
#define LSEQ 1000
#define BN_EPS 1e-5f
#define W1O 985
#define W2O 970
#define W3O 955
#define C1S 988          // g_c1o row stride (floats), layout [b][32 ch][C1S]
#define C2S 976          // g_c2o row stride (floats), layout [b][32 ch][C2S]

// ---- dtype flag: 1 if float inputs are f32, 0 if bf16 (measured: f32 on this harness) ----
__device__ int g_isf32;

__device__ __forceinline__ float LD(const void* p, int i, int f){
    return f ? ((const float*)p)[i] : b2f(((const bf16*)p)[i]);
}

// f32 -> bf16 bits, round-to-nearest-even
__device__ __forceinline__ unsigned short f2b(float x){
    unsigned u = __float_as_uint(x);
    return (unsigned short)((u + 0x7FFFu + ((u >> 16) & 1u)) >> 16);
}
__device__ __forceinline__ float bb2f(unsigned short h){
    return __uint_as_float(((unsigned)h) << 16);
}

__global__ void k_dtype(const void* x){
    if (threadIdx.x != 0 || blockIdx.x != 0) return;
    const unsigned short* u = (const unsigned short*)x;
    int insane = 0;
    for (int i = 0; i < 512; i++){
        unsigned short h = u[i];
        int ex = (h >> 7) & 0xFF;
        if (!(h == 0 || (ex >= 96 && ex <= 142))) insane++;
    }
    g_isf32 = (insane > 50) ? 1 : 0;
}

// ---- intermediates in device globals ----
__device__ float g_hA[N_NODES*32];
__device__ float g_hB[N_NODES*32];
__device__ float g_pooled[NB*32];
__device__ float g_xd[NB*128];
__device__ float g_P[16*26*32];
__device__ float g_wsum[32*128];
__device__ float g_xdb[NB*32];
__device__ float g_xcm[NB*32];
__device__ float g_xcf[NB*128];
__device__ float g_z1[NB*1024];
__device__ float g_z2[NB*256];
__device__ float g_c1o[NB*32*C1S];   // 32.4 MB, [b][o][w]
__device__ float g_c2o[NB*32*C2S];   // 32.0 MB, [b][o][w]
// pre-packed conv weights in per-lane B-FRAGMENT order (s8v granularity):
// s8v index = ktg*256 + ogrp*128 + hl*64 + lane
__device__ __attribute__((aligned(16))) unsigned short g_wf[2][32768];
// CSR of the (fixed) edge list, destination-major
__device__ int g_deg[N_NODES];
__device__ int g_cur[N_NODES];
__device__ int g_rowptr[N_NODES + 1];
__device__ int g_csrc[N_EDGES];
__device__ int g_gstart[NB + 1];     // per-graph node ranges (batch is sorted)

__global__ void k_zero_xcm(){ g_xcm[blockIdx.x*256 + threadIdx.x] = 0.f; }   // grid 32

// ---- CSR build (once per launch; edge list reused by all 5 layers) ----
__global__ void k_zero_deg(){ g_deg[blockIdx.x*256 + threadIdx.x] = 0; }     // grid 64
__global__ void k_count(const int* __restrict__ ei){
    int e = blockIdx.x*256 + threadIdx.x;                                    // grid 256
    atomicAdd(&g_deg[ei[N_EDGES + e]], 1);
}
__global__ __launch_bounds__(1024) void k_scan(){                            // 1 block
    __shared__ int part[1024];
    int t = threadIdx.x;
    int base = t*16;
    int s = 0;
    #pragma unroll
    for (int i = 0; i < 16; i++) s += g_deg[base + i];
    part[t] = s;
    __syncthreads();
    for (int off = 1; off < 1024; off <<= 1){
        int v = (t >= off) ? part[t - off] : 0;
        __syncthreads();
        part[t] += v;
        __syncthreads();
    }
    int run = (t == 0) ? 0 : part[t - 1];
    for (int i = 0; i < 16; i++){
        g_rowptr[base + i] = run;
        g_cur[base + i] = run;
        run += g_deg[base + i];
    }
    if (t == 1023) g_rowptr[N_NODES] = run;
}
__global__ void k_fill(const int* __restrict__ ei){
    int e = blockIdx.x*256 + threadIdx.x;                                    // grid 256
    int d = ei[N_EDGES + e];
    int slot = atomicAdd(&g_cur[d], 1);
    g_csrc[slot] = ei[e];
}
__global__ void k_ranges(const int* __restrict__ batch){                     // 1 block, 256 thr
    int b = threadIdx.x;
    int lo = 0, hi = N_NODES;
    while (lo < hi){ int mid = (lo + hi) >> 1; if (batch[mid] < b) lo = mid + 1; else hi = mid; }
    g_gstart[b] = lo;
    if (b == 0) g_gstart[NB] = N_NODES;
}

// ---- weight pre-pack into fragment order ----
__global__ void k_wpack(const void* w2, const void* w3){
    const int F = g_isf32;
    int idx = blockIdx.x*256 + threadIdx.x;      // 65536 threads
    int sel = idx >> 15;
    int r = idx & 32767;
    int j = r & 7;
    int lane = (r >> 3) & 63;
    int hl = (r >> 9) & 1;
    int ogrp = (r >> 10) & 1;
    int ktg = r >> 11;
    int c = (lane >> 4)*8 + j;
    int o = ogrp*16 + (lane & 15);
    const void* Wt = sel ? w3 : w2;
    float wv = LD(Wt, o*512 + c*16 + ktg, F);
    unsigned short h = f2b(wv);
    g_wf[sel][r] = hl ? f2b(wv - bb2f(h)) : h;
}

// ---------------- GIN branch (CSR gather fused into the MLP kernels) ----------

__global__ __launch_bounds__(256) void k_proj78(const void* x, const void* W1)
{
    const int F = g_isf32;
    __shared__ float sW1[78*32];
    __shared__ float sx[8][78];
    int tid = threadIdx.x;
    for (int i = tid; i < 78*32; i += 256) sW1[i] = LD(W1, i, F);
    int nodeBase = blockIdx.x * 8;
    for (int i = tid; i < 8*78; i += 256){
        int ln = i / 78, f = i - ln*78;
        sx[ln][f] = LD(x, (nodeBase + ln)*78 + f, F);
    }
    __syncthreads();
    int ln = tid >> 5, j = tid & 31;
    float a = 0.f;
    #pragma unroll 6
    for (int i = 0; i < 78; i++) a += sx[ln][i] * sW1[i*32 + j];
    g_hA[(nodeBase + ln)*32 + j] = a;
}

// hA -> hB ; inline CSR gather replaces the scatter+agg kernels
__global__ __launch_bounds__(256) void k_gin1b(
    const void* b1, const void* W2, const void* b2,
    const void* bng, const void* bnb, const void* bnm, const void* bnv)
{
    const int F = g_isf32;
    __shared__ float sW2[32*32];
    __shared__ float sb1[32], sb2[32], sA[32], sB[32];
    __shared__ float st[8][32];
    int tid = threadIdx.x;
    for (int i = tid; i < 1024; i += 256) sW2[i] = LD(W2, i, F);
    if (tid < 32){
        sb1[tid] = LD(b1, tid, F); sb2[tid] = LD(b2, tid, F);
        float inv = LD(bng, tid, F) * rsqrtf(LD(bnv, tid, F) + BN_EPS);
        sA[tid] = inv;
        sB[tid] = LD(bnb, tid, F) - LD(bnm, tid, F) * inv;
    }
    __syncthreads();
    int ln = tid >> 5, j = tid & 31;
    int n = blockIdx.x*8 + ln;
    int rs = g_rowptr[n], re2 = g_rowptr[n + 1];
    float agg = 0.f;
    for (int e = rs; e < re2; e++) agg += g_hA[g_csrc[e]*32 + j];
    st[ln][j] = fmaxf(g_hA[n*32 + j] + agg + sb1[j], 0.f);
    __syncthreads();
    float t2 = sb2[j];
    #pragma unroll
    for (int i = 0; i < 32; i++) t2 += st[ln][i] * sW2[i*32 + j];
    t2 = fmaxf(t2, 0.f);
    g_hB[n*32 + j] = t2 * sA[j] + sB[j];
}

// alternating hB->hA (l even) / hA->hB (l odd)
__global__ __launch_bounds__(256) void k_gin32L(
    const void* W1, const void* b1, const void* W2, const void* b2,
    const void* bng, const void* bnb, const void* bnm, const void* bnv, int l)
{
    const int F = g_isf32;
    const float* hin = (l & 1) ? g_hA : g_hB;
    float* hout = (l & 1) ? g_hB : g_hA;
    const int oW = l*1024, ob = l*32, obn = (l+1)*32;
    __shared__ float sW1[32*32], sW2[32*32];
    __shared__ float sb1[32], sb2[32], sA[32], sB[32];
    __shared__ float sh[8][32], st[8][32];
    int tid = threadIdx.x;
    for (int i = tid; i < 1024; i += 256){ sW1[i] = LD(W1, oW + i, F); sW2[i] = LD(W2, oW + i, F); }
    if (tid < 32){
        sb1[tid] = LD(b1, ob + tid, F); sb2[tid] = LD(b2, ob + tid, F);
        float inv = LD(bng, obn + tid, F) * rsqrtf(LD(bnv, obn + tid, F) + BN_EPS);
        sA[tid] = inv;
        sB[tid] = LD(bnb, obn + tid, F) - LD(bnm, obn + tid, F) * inv;
    }
    int ln = tid >> 5, j = tid & 31;
    int n = blockIdx.x*8 + ln;
    int rs = g_rowptr[n], re2 = g_rowptr[n + 1];
    float agg = 0.f;
    for (int e = rs; e < re2; e++) agg += hin[g_csrc[e]*32 + j];
    sh[ln][j] = hin[n*32 + j] + agg;
    __syncthreads();
    float t1 = sb1[j];
    #pragma unroll
    for (int i = 0; i < 32; i++) t1 += sh[ln][i] * sW1[i*32 + j];
    st[ln][j] = fmaxf(t1, 0.f);
    __syncthreads();
    float t2 = sb2[j];
    #pragma unroll
    for (int i = 0; i < 32; i++) t2 += st[ln][i] * sW2[i*32 + j];
    t2 = fmaxf(t2, 0.f);
    hout[n*32 + j] = t2 * sA[j] + sB[j];
}

// range-based pool over sorted batch (no atomics); final h lives in g_hB
__global__ __launch_bounds__(256) void k_pool(){
    __shared__ float red[8][32];
    int b = blockIdx.x, tid = threadIdx.x;
    int j = tid & 31, sub = tid >> 5;
    int s = g_gstart[b], e = g_gstart[b + 1];
    float a = 0.f;
    for (int n = s + sub; n < e; n += 8) a += g_hB[n*32 + j];
    red[sub][j] = a;
    __syncthreads();
    if (sub == 0){
        float r = red[0][j] + red[1][j] + red[2][j] + red[3][j]
                + red[4][j] + red[5][j] + red[6][j] + red[7][j];
        g_pooled[b*32 + j] = r;
    }
}

__global__ void k_xd(const void* W, const void* bias){
    const int F = g_isf32;
    __shared__ float sp[32];
    int b = blockIdx.x, j = threadIdx.x;
    if (j < 32) sp[j] = g_pooled[b*32 + j];
    __syncthreads();
    float a = LD(bias, j, F);
    #pragma unroll
    for (int i = 0; i < 32; i++) a += sp[i] * LD(W, i*128 + j, F);
    g_xd[b*128 + j] = fmaxf(a, 0.f);
}

// ---------------- conv1 via 26-row embedding table ----------------

__global__ void k_P(const void* embed, const void* c1W){
    const int F = g_isf32;
    int idx = blockIdx.x*256 + threadIdx.x;
    if (idx >= 16*26*32) return;
    int o = idx & 31;
    int t = (idx >> 5) % 26;
    int k = idx / (32*26);
    float a = 0.f;
    for (int c = 0; c < 128; c++)
        a += LD(embed, t*128 + c, F) * LD(c1W, o*4096 + c*16 + k, F);
    g_P[(k*26 + t)*32 + o] = a;
}

__global__ void k_wsum(const void* c1W){
    const int F = g_isf32;
    int idx = blockIdx.x*256 + threadIdx.x;
    int o = idx >> 7, c = idx & 127;
    float a = 0.f;
    #pragma unroll
    for (int k = 0; k < 16; k++) a += LD(c1W, o*4096 + (128 + c)*16 + k, F);
    g_wsum[o*128 + c] = a;
}

__global__ void k_xdbias(const void* c1b){
    const int F = g_isf32;
    int idx = blockIdx.x*256 + threadIdx.x;
    int b = idx >> 5, o = idx & 31;
    float a = LD(c1b, o, F);
    for (int c = 0; c < 128; c++) a += g_xd[b*128 + c] * g_wsum[o*128 + c];
    g_xdb[idx] = a;
}

// writes [b][o][w] layout (stride C1S). o = tid&31 -> table-gather bank = lane
__global__ __launch_bounds__(256) void k_conv1L(
    const int* __restrict__ target,
    const void* g, const void* be, const void* m, const void* v, int obn)
{
    const int F = g_isf32;
    __shared__ float sP[16*26*32];
    __shared__ int   stg[LSEQ];
    __shared__ float sxb[32], sA[32], sB[32];
    int b = blockIdx.x, tid = threadIdx.x;
    for (int i = tid; i < 16*26*32; i += 256) sP[i] = g_P[i];
    for (int i = tid; i < LSEQ; i += 256) stg[i] = target[b*LSEQ + i];
    if (tid < 32){
        sxb[tid] = g_xdb[b*32 + tid];
        float inv = LD(g, obn + tid, F) * rsqrtf(LD(v, obn + tid, F) + BN_EPS);
        sA[tid] = inv;
        sB[tid] = LD(be, obn + tid, F) - LD(m, obn + tid, F) * inv;
    }
    __syncthreads();
    int o = tid & 31, wsub = tid >> 5;
    float xb = sxb[o], aa = sA[o], bb = sB[o];
    for (int w = wsub; w < W1O; w += 8){
        float a = xb;
        #pragma unroll
        for (int k = 0; k < 16; k++)
            a += sP[(k*26 + stg[w + k])*32 + o];
        g_c1o[(b*32 + o)*C1S + w] = fmaxf(a * aa + bb, 0.f);
    }
}

// ---------------- conv2/conv3 via MFMA, double-bf16 split (r12, unchanged) ----

#define CT_W 128
#define CT_R 144     // 128 + 15 halo, padded
#define CPAD 40      // c-row pad: 80 B = 16B-aligned rows

__global__ __launch_bounds__(256) void k_cmfma(
    int sel, int Wvalid, int Wout, int inStride,
    const void* bias, const void* g, const void* be,
    const void* m, const void* v, int obn)
{
    const int F = g_isf32;
    const float* in = (sel == 0) ? g_c1o : g_c2o;
    __shared__ __attribute__((aligned(16))) unsigned short sAh[CT_R*CPAD]; // 11520 B
    __shared__ __attribute__((aligned(16))) unsigned short sAl[CT_R*CPAD]; // 11520 B
    __shared__ float sSc[32], sOf[32];
    int tid = threadIdx.x;
    int b = blockIdx.x >> 3;
    int tile = blockIdx.x & 7;
    int wbase = tile * CT_W;

    for (int c = 0; c < 32; c++){
        const float* src = in + (b*32 + c)*inStride;
        if (tid < CT_R){
            int wg_ = wbase + tid;
            float xv = (wg_ < Wvalid) ? src[wg_] : 0.f;
            unsigned short h = f2b(xv);
            sAh[tid*CPAD + c] = h;
            sAl[tid*CPAD + c] = f2b(xv - bb2f(h));
        }
    }
    if (tid < 32){
        float inv = LD(g, obn + tid, F) * rsqrtf(LD(v, obn + tid, F) + BN_EPS);
        sSc[tid] = inv;
        sOf[tid] = LD(be, obn + tid, F) + (LD(bias, tid, F) - LD(m, obn + tid, F)) * inv;
    }
    __syncthreads();                 // the ONLY barrier

    int lane = tid & 63;
    int wv = tid >> 6;
    int ml = lane & 15, quad = lane >> 4;
    int wgrp = wv & 1;
    int ogrp = wv >> 1;

    const s8v* wfb = (const s8v*)&g_wf[sel][0] + ogrp*128 + lane;

    f4v acc[4];
    #pragma unroll
    for (int mt = 0; mt < 4; mt++) acc[mt] = (f4v){0.f, 0.f, 0.f, 0.f};

    s8v nbh = wfb[0], nbl = wfb[64];
    for (int ktg = 0; ktg < 16; ktg++){
        s8v bh = nbh, bl = nbl;
        if (ktg < 15){
            nbh = wfb[(ktg + 1)*256];
            nbl = wfb[(ktg + 1)*256 + 64];
        }
        #pragma unroll
        for (int mt = 0; mt < 4; mt++){
            int row = wgrp*64 + mt*16 + ml + ktg;
            const int aidx = row*CPAD + quad*8;
            s8v ah = *(const s8v*)&sAh[aidx];
            s8v al = *(const s8v*)&sAl[aidx];
            acc[mt] = __builtin_amdgcn_mfma_f32_16x16x32_bf16(ah, bh, acc[mt], 0, 0, 0);
            acc[mt] = __builtin_amdgcn_mfma_f32_16x16x32_bf16(ah, bl, acc[mt], 0, 0, 0);
            acc[mt] = __builtin_amdgcn_mfma_f32_16x16x32_bf16(al, bh, acc[mt], 0, 0, 0);
        }
    }

    int o = ogrp*16 + ml;
    float sc = sSc[o], of = sOf[o];
    #pragma unroll
    for (int mt = 0; mt < 4; mt++){
        int w0 = wbase + wgrp*64 + mt*16 + quad*4;
        f4v a = acc[mt];
        float y0 = fmaxf(a.x*sc + of, 0.f);
        float y1 = fmaxf(a.y*sc + of, 0.f);
        float y2 = fmaxf(a.z*sc + of, 0.f);
        float y3 = fmaxf(a.w*sc + of, 0.f);
        if (sel == 0){
            float* dst = &g_c2o[(b*32 + o)*C2S + w0];
            if (w0 + 3 < Wout){
                *(float4*)dst = make_float4(y0, y1, y2, y3);
            } else if (w0 < Wout){
                dst[0] = y0;
                if (w0+1 < Wout) dst[1] = y1;
                if (w0+2 < Wout) dst[2] = y2;
                if (w0+3 < Wout) dst[3] = y3;
            }
        } else {
            if (w0 < Wout){
                float mx = y0;
                if (w0+1 < Wout) mx = fmaxf(mx, y1);
                if (w0+2 < Wout) mx = fmaxf(mx, y2);
                if (w0+3 < Wout) mx = fmaxf(mx, y3);
                atomicMax((int*)&g_xcm[b*32 + o], __float_as_int(mx));
            }
        }
    }
}

// ---------------- FC tail ----------------

__global__ void k_xcf(const void* W, const void* bias,
                      const void* g, const void* be, const void* m, const void* v){
    const int F = g_isf32;
    __shared__ float sp[32];
    int b = blockIdx.x, j = threadIdx.x;
    if (j < 32) sp[j] = g_xcm[b*32 + j];
    __syncthreads();
    float a = LD(bias, j, F);
    #pragma unroll
    for (int i = 0; i < 32; i++) a += sp[i] * LD(W, i*128 + j, F);
    float inv = LD(g, j, F) * rsqrtf(LD(v, j, F) + BN_EPS);
    a = (a - LD(m, j, F)) * inv + LD(be, j, F);
    g_xcf[b*128 + j] = fmaxf(a, 0.f);
}

__global__ __launch_bounds__(256) void k_fc1(const void* W, const void* bias){
    const int F = g_isf32;
    __shared__ float sz[256];
    int b = blockIdx.x >> 2;
    int j = ((blockIdx.x & 3) << 8) + threadIdx.x;
    int t = threadIdx.x;
    sz[t] = (t < 128) ? g_xd[b*128 + t] : g_xcf[b*128 + (t - 128)];
    __syncthreads();
    float a = LD(bias, j, F);
    for (int i = 0; i < 256; i++) a += sz[i] * LD(W, i*1024 + j, F);
    g_z1[b*1024 + j] = fmaxf(a, 0.f);
}

__global__ __launch_bounds__(1024) void k_fc2(const void* W, const void* bias){
    const int F = g_isf32;
    __shared__ float sz[1024];
    __shared__ float sp[4][256];
    int b = blockIdx.x, t = threadIdx.x;
    sz[t] = g_z1[b*1024 + t];
    __syncthreads();
    int j = t & 255, kq = t >> 8;
    float a = 0.f;
    #pragma unroll 8
    for (int i = 0; i < 256; i++)
        a += sz[kq*256 + i] * LD(W, (kq*256 + i)*256 + j, F);
    sp[kq][j] = a;
    __syncthreads();
    if (t < 256){
        float r = sp[0][t] + sp[1][t] + sp[2][t] + sp[3][t] + LD(bias, t, F);
        g_z2[b*256 + t] = fmaxf(r, 0.f);
    }
}

__global__ void k_out(const void* W, const void* bias, void* out){
    const int F = g_isf32;
    __shared__ float red[256];
    int b = blockIdx.x, t = threadIdx.x;
    red[t] = g_z2[b*256 + t] * LD(W, t, F);
    __syncthreads();
    for (int s = 128; s > 0; s >>= 1){
        if (t < s) red[t] += red[t + s];
        __syncthreads();
    }
    if (t == 0){
        float r = red[0] + LD(bias, 0, F);
        if (F) ((float*)out)[b] = r;
        else   ((bf16*)out)[b] = __float2bfloat16(r);
    }
}

// ---------------- launch ----------------

extern "C" void kernel_launch(void* const* d_in, const int* in_sizes, int n_in,
                              void* d_out, int out_size, void* d_ws, size_t ws_size,
                              hipStream_t stream)
{
    (void)in_sizes; (void)n_in; (void)out_size; (void)d_ws; (void)ws_size;
    const void* x      = d_in[0];
    const int*  ei     = (const int*)d_in[1];
    const int*  batch  = (const int*)d_in[2];
    const int*  target = (const int*)d_in[3];
    const void* g1W1 = d_in[4];  const void* g1b1 = d_in[5];
    const void* g1W2 = d_in[6];  const void* g1b2 = d_in[7];
    const void* gW1  = d_in[8];  const void* gb1  = d_in[9];
    const void* gW2  = d_in[10]; const void* gb2  = d_in[11];
    const void* bng  = d_in[12]; const void* bnb  = d_in[13];
    const void* bnm  = d_in[14]; const void* bnv  = d_in[15];
    const void* fcxdW = d_in[16]; const void* fcxdb = d_in[17];
    const void* embed = d_in[18];
    const void* c1W = d_in[19]; const void* c1b = d_in[20];
    const void* c2W = d_in[21]; const void* c2b = d_in[22];
    const void* c3W = d_in[23]; const void* c3b = d_in[24];
    const void* cbng = d_in[25]; const void* cbnb = d_in[26];
    const void* cbnm = d_in[27]; const void* cbnv = d_in[28];
    const void* fcxcW = d_in[29]; const void* fcxcb = d_in[30];
    const void* bnfcg = d_in[31]; const void* bnfcb = d_in[32];
    const void* bnfcm = d_in[33]; const void* bnfcv = d_in[34];
    const void* fc1W = d_in[35]; const void* fc1b = d_in[36];
    const void* fc2W = d_in[37]; const void* fc2b = d_in[38];
    const void* outW = d_in[39]; const void* outb = d_in[40];

    k_dtype<<<1, 64, 0, stream>>>(x);
    k_wpack<<<256, 256, 0, stream>>>(c2W, c3W);

    // ---- CSR build (edge list is layer-invariant) ----
    k_zero_deg<<<N_NODES/256, 256, 0, stream>>>();
    k_count<<<N_EDGES/256, 256, 0, stream>>>(ei);
    k_scan<<<1, 1024, 0, stream>>>();
    k_fill<<<N_EDGES/256, 256, 0, stream>>>(ei);
    k_ranges<<<1, 256, 0, stream>>>(batch);

    // ---- GIN chain (gather fused; h ping-pongs hA->hB->hA->...) ----
    k_proj78<<<N_NODES/8, 256, 0, stream>>>(x, g1W1);
    k_zero_xcm<<<NB*32/256, 256, 0, stream>>>();
    k_gin1b<<<N_NODES/8, 256, 0, stream>>>(g1b1, g1W2, g1b2, bng, bnb, bnm, bnv);
    for (int l = 0; l < 4; l++){
        k_gin32L<<<N_NODES/8, 256, 0, stream>>>(gW1, gb1, gW2, gb2,
                                                bng, bnb, bnm, bnv, l);
    }
    // ---- pool + xd ----
    k_pool<<<NB, 256, 0, stream>>>();
    k_xd<<<NB, 128, 0, stream>>>(fcxdW, fcxdb);
    // ---- conv1 prep ----
    k_P<<<(16*26*32 + 255)/256, 256, 0, stream>>>(embed, c1W);
    k_wsum<<<16, 256, 0, stream>>>(c1W);
    k_xdbias<<<32, 256, 0, stream>>>(c1b);
    // ---- conv chain ----
    k_conv1L<<<NB, 256, 0, stream>>>(target, cbng, cbnb, cbnm, cbnv, 0);
    k_cmfma<<<NB*8, 256, 0, stream>>>(0, W1O, W2O, C1S,
                                      c2b, cbng, cbnb, cbnm, cbnv, 32);
    k_cmfma<<<NB*8, 256, 0, stream>>>(1, W2O, W3O, C2S,
                                      c3b, cbng, cbnb, cbnm, cbnv, 64);
    // ---- FC tail ----
    k_xcf<<<NB, 128, 0, stream>>>(fcxcW, fcxcb, bnfcg, bnfcb, bnfcm, bnfcv);
    k_fc1<<<NB*4, 256, 0, stream>>>(fc1W, fc1b);
    k_fc2<<<NB, 1024, 0, stream>>>(fc2W, fc2b);
    k_out<<<NB, 256, 0, stream>>>(outW, outb, d_out);
}